// Round 2
// baseline (1806.872 us; speedup 1.0000x reference)
//
#include <hip/hip_runtime.h>
#include <hip/hip_bf16.h>
#include <math.h>

typedef __hip_bfloat16 bf16;

constexpr int BB    = 2;      // batch
constexpr int LL    = 4096;   // seq len
constexpr int DM    = 1024;   // d_model
constexpr int DIN   = 2048;   // d_inner
constexpr int HH    = 32;     // n_heads
constexpr int PP    = 64;     // head_dim
constexpr int NSD   = 128;    // d_state
constexpr int CONVD = 2304;   // d_inner + 2*d_state
constexpr int DPROJ = 4384;   // 2*d_inner + 2*d_state + n_heads
constexpr int CHK   = 64;     // chunk size
constexpr int NC    = 64;     // chunks per batch (L/CHK)
constexpr int ROWS  = BB * LL; // 8192

__device__ __forceinline__ float b2f(bf16 v) { return __bfloat162float(v); }
__device__ __forceinline__ bf16  f2b(float f) { return __float2bfloat16(f); }
__device__ __forceinline__ float lo16(unsigned u) { return __uint_as_float(u << 16); }
__device__ __forceinline__ float hi16(unsigned u) { return __uint_as_float(u & 0xffff0000u); }

// ---------------------------------------------------------------------------
// in_proj GEMM: [8192 x 1024] fp32 @ [1024 x 4384] fp32, split bf16 outputs:
//   cols [0,2048)      -> zb   (bf16, stride DIN)
//   cols [2048,4352)   -> xbcb (bf16, stride CONVD)
//   cols [4352,4384)   -> dtraw (fp32, stride HH)
// Tile boundaries land exactly on the splits (2048 and 4352 are 64-aligned).
// ---------------------------------------------------------------------------
__global__ __launch_bounds__(256) void gemm_inproj(
    const float* __restrict__ A, const float* __restrict__ Bp,
    bf16* __restrict__ zb, bf16* __restrict__ xbcb, float* __restrict__ dtraw) {
  constexpr int M = ROWS, N = DPROJ, K = DM;
  __shared__ float As[32][68];
  __shared__ float Bs[32][68];
  const int t  = threadIdx.x;
  const int m0 = blockIdx.y * 64;
  const int n0 = blockIdx.x * 64;
  const int tx = t & 15, ty = t >> 4;
  const bool nfull = (n0 + 64 <= N);
  float acc[4][4] = {};

  for (int k0 = 0; k0 < K; k0 += 32) {
#pragma unroll
    for (int i = 0; i < 2; ++i) {
      int f  = t + i * 256;
      int kf = f & 7;
      int m  = f >> 3;
      float4 v = *(const float4*)&A[(size_t)(m0 + m) * K + k0 + kf * 4];
      As[kf * 4 + 0][m] = v.x; As[kf * 4 + 1][m] = v.y;
      As[kf * 4 + 2][m] = v.z; As[kf * 4 + 3][m] = v.w;
    }
#pragma unroll
    for (int i = 0; i < 2; ++i) {
      int f  = t + i * 256;
      int nf = f & 15;
      int k  = f >> 4;
      float4 v;
      if (nfull) {
        v = *(const float4*)&Bp[(size_t)(k0 + k) * N + n0 + nf * 4];
      } else {
        int nb = n0 + nf * 4;
        const float* bp = &Bp[(size_t)(k0 + k) * N];
        v.x = (nb + 0 < N) ? bp[nb + 0] : 0.f;
        v.y = (nb + 1 < N) ? bp[nb + 1] : 0.f;
        v.z = (nb + 2 < N) ? bp[nb + 2] : 0.f;
        v.w = (nb + 3 < N) ? bp[nb + 3] : 0.f;
      }
      *(float4*)&Bs[k][nf * 4] = v;
    }
    __syncthreads();
#pragma unroll
    for (int kk = 0; kk < 32; ++kk) {
      float4 a = *(const float4*)&As[kk][ty * 4];
      float4 b = *(const float4*)&Bs[kk][tx * 4];
      acc[0][0] += a.x * b.x; acc[0][1] += a.x * b.y; acc[0][2] += a.x * b.z; acc[0][3] += a.x * b.w;
      acc[1][0] += a.y * b.x; acc[1][1] += a.y * b.y; acc[1][2] += a.y * b.z; acc[1][3] += a.y * b.w;
      acc[2][0] += a.z * b.x; acc[2][1] += a.z * b.y; acc[2][2] += a.z * b.z; acc[2][3] += a.z * b.w;
      acc[3][0] += a.w * b.x; acc[3][1] += a.w * b.y; acc[3][2] += a.w * b.z; acc[3][3] += a.w * b.w;
    }
    __syncthreads();
  }
#pragma unroll
  for (int i = 0; i < 4; ++i) {
    int m = m0 + ty * 4 + i;
    if (n0 < DIN) {
      bf16* p = &zb[(size_t)m * DIN + n0 + tx * 4];
      p[0] = f2b(acc[i][0]); p[1] = f2b(acc[i][1]);
      p[2] = f2b(acc[i][2]); p[3] = f2b(acc[i][3]);
    } else if (n0 < DIN + CONVD) {
      bf16* p = &xbcb[(size_t)m * CONVD + (n0 - DIN) + tx * 4];
      p[0] = f2b(acc[i][0]); p[1] = f2b(acc[i][1]);
      p[2] = f2b(acc[i][2]); p[3] = f2b(acc[i][3]);
    } else {
      int nb = (n0 - DIN - CONVD) + tx * 4;
#pragma unroll
      for (int j = 0; j < 4; ++j)
        if (nb + j < HH) dtraw[(size_t)m * HH + nb + j] = acc[i][j];
    }
  }
}

// ---------------------------------------------------------------------------
// out_proj GEMM: A bf16 [8192 x 2048] @ B fp32 [2048 x 1024] -> C fp32.
// ---------------------------------------------------------------------------
__global__ __launch_bounds__(256) void gemm_out(const bf16* __restrict__ A,
                                                const float* __restrict__ Bp,
                                                float* __restrict__ C) {
  constexpr int N = DM, K = DIN;
  __shared__ float As[32][68];
  __shared__ float Bs[32][68];
  const int t  = threadIdx.x;
  const int m0 = blockIdx.y * 64;
  const int n0 = blockIdx.x * 64;
  const int tx = t & 15, ty = t >> 4;
  float acc[4][4] = {};

  for (int k0 = 0; k0 < K; k0 += 32) {
    { // A tile 64m x 32k bf16: 2048 elems, 8 per thread (uint4)
      int m  = t >> 2;
      int kg = (t & 3) * 8;
      uint4 v = *(const uint4*)&A[(size_t)(m0 + m) * K + k0 + kg];
      As[kg + 0][m] = lo16(v.x); As[kg + 1][m] = hi16(v.x);
      As[kg + 2][m] = lo16(v.y); As[kg + 3][m] = hi16(v.y);
      As[kg + 4][m] = lo16(v.z); As[kg + 5][m] = hi16(v.z);
      As[kg + 6][m] = lo16(v.w); As[kg + 7][m] = hi16(v.w);
    }
#pragma unroll
    for (int i = 0; i < 2; ++i) {
      int f  = t + i * 256;
      int nf = f & 15;
      int k  = f >> 4;
      float4 v = *(const float4*)&Bp[(size_t)(k0 + k) * N + n0 + nf * 4];
      *(float4*)&Bs[k][nf * 4] = v;
    }
    __syncthreads();
#pragma unroll
    for (int kk = 0; kk < 32; ++kk) {
      float4 a = *(const float4*)&As[kk][ty * 4];
      float4 b = *(const float4*)&Bs[kk][tx * 4];
      acc[0][0] += a.x * b.x; acc[0][1] += a.x * b.y; acc[0][2] += a.x * b.z; acc[0][3] += a.x * b.w;
      acc[1][0] += a.y * b.x; acc[1][1] += a.y * b.y; acc[1][2] += a.y * b.z; acc[1][3] += a.y * b.w;
      acc[2][0] += a.z * b.x; acc[2][1] += a.z * b.y; acc[2][2] += a.z * b.z; acc[2][3] += a.z * b.w;
      acc[3][0] += a.w * b.x; acc[3][1] += a.w * b.y; acc[3][2] += a.w * b.z; acc[3][3] += a.w * b.w;
    }
    __syncthreads();
  }
#pragma unroll
  for (int i = 0; i < 4; ++i) {
    int m = m0 + ty * 4 + i;
    *(float4*)&C[(size_t)m * N + n0 + tx * 4] =
        make_float4(acc[i][0], acc[i][1], acc[i][2], acc[i][3]);
  }
}

// ---------------------------------------------------------------------------
// Depthwise causal conv1d (k=4) + bias + silu + splits; dt softplus; dtA.
// ---------------------------------------------------------------------------
__global__ __launch_bounds__(256) void conv_act(
    const bf16* __restrict__ xbc, const float* __restrict__ dtraw,
    const float* __restrict__ convw, const float* __restrict__ convb,
    const float* __restrict__ dtb, const float* __restrict__ alog,
    bf16* __restrict__ xs, float* __restrict__ Bm, float* __restrict__ Cm,
    float* __restrict__ dtv, float* __restrict__ dtA) {
  const int row = blockIdx.x;
  const int l   = row & (LL - 1);
  const int t   = threadIdx.x;
  if (t < HH) {
    float raw = dtraw[(size_t)row * HH + t] + dtb[t];
    float dt  = (raw > 20.f) ? raw : log1pf(expf(raw));
    dtv[(size_t)row * HH + t] = dt;
    dtA[(size_t)row * HH + t] = -expf(alog[t]) * dt;
  }
  for (int ch = t; ch < CONVD; ch += 256) {
    float acc = convb[ch];
#pragma unroll
    for (int k = 0; k < 4; ++k) {
      int ll = l - 3 + k;
      if (ll >= 0)
        acc += b2f(xbc[(size_t)(row - 3 + k) * CONVD + ch]) * convw[k * CONVD + ch];
    }
    float s = acc / (1.f + expf(-acc)); // silu
    if (ch < DIN) {
      xs[(size_t)row * DIN + ch] = f2b(s);
    } else if (ch < DIN + NSD) {
      Bm[(size_t)row * NSD + (ch - DIN)] = s;
    } else {
      Cm[(size_t)row * NSD + (ch - DIN - NSD)] = s;
    }
  }
}

// ---------------------------------------------------------------------------
// G[b,c,l,s] = dot(C[l,:], B[s,:]) over d_state (head-independent).
// ---------------------------------------------------------------------------
__global__ __launch_bounds__(256) void gmat(const float* __restrict__ Bm,
                                            const float* __restrict__ Cm,
                                            float* __restrict__ G) {
  const int sh = blockIdx.x;
  const int c = blockIdx.y, b = blockIdx.z;
  const int row0 = (b * NC + c) * CHK;
  __shared__ float CshT[NSD][CHK + 1];
  __shared__ float BshT[NSD][33];
  const int t = threadIdx.x;
#pragma unroll
  for (int i = 0; i < 8; ++i) {
    int f = t + i * 256;
    int l = f >> 5, n4 = f & 31;
    float4 v = *(const float4*)&Cm[(size_t)(row0 + l) * NSD + n4 * 4];
    CshT[n4 * 4 + 0][l] = v.x; CshT[n4 * 4 + 1][l] = v.y;
    CshT[n4 * 4 + 2][l] = v.z; CshT[n4 * 4 + 3][l] = v.w;
  }
#pragma unroll
  for (int i = 0; i < 4; ++i) {
    int f = t + i * 256;
    int s = f >> 5, n4 = f & 31;
    float4 v = *(const float4*)&Bm[(size_t)(row0 + sh * 32 + s) * NSD + n4 * 4];
    BshT[n4 * 4 + 0][s] = v.x; BshT[n4 * 4 + 1][s] = v.y;
    BshT[n4 * 4 + 2][s] = v.z; BshT[n4 * 4 + 3][s] = v.w;
  }
  __syncthreads();
  const int l  = t & 63;
  const int s0 = (t >> 6) * 8;
  float acc[8] = {};
  for (int n = 0; n < NSD; ++n) {
    float cv = CshT[n][l];
#pragma unroll
    for (int j = 0; j < 8; ++j) acc[j] += cv * BshT[n][s0 + j];
  }
  float* gp = &G[((size_t)(b * NC + c) * CHK + l) * CHK + sh * 32 + s0];
  *(float4*)&gp[0] = make_float4(acc[0], acc[1], acc[2], acc[3]);
  *(float4*)&gp[4] = make_float4(acc[4], acc[5], acc[6], acc[7]);
}

// ---------------------------------------------------------------------------
// Per (b,c,h): cumsum(dtA), decay-masked G -> Y_diag (bf16), chunk states (bf16).
// ---------------------------------------------------------------------------
__global__ __launch_bounds__(256) void ssd_chunk(
    const float* __restrict__ G, const bf16* __restrict__ xsp,
    const float* __restrict__ Bm, const float* __restrict__ dtv,
    const float* __restrict__ dtA,
    bf16* __restrict__ y, bf16* __restrict__ states, float* __restrict__ cumA) {
  const int h = blockIdx.x, c = blockIdx.y, b = blockIdx.z;
  const int row0 = (b * NC + c) * CHK;
  __shared__ float un[CHK * NSD];      // GM (stride 65) then B chunk (stride 128)
  __shared__ float xds[CHK][CHK + 4];
  __shared__ float sA[CHK], cA[CHK], dec[CHK], sdt[CHK];
  const int t = threadIdx.x;
  if (t < CHK) {
    sA[t]  = dtA[(size_t)(row0 + t) * HH + h];
    sdt[t] = dtv[(size_t)(row0 + t) * HH + h];
  }
  __syncthreads();
  if (t == 0) {
    float s = 0.f;
    for (int i = 0; i < CHK; ++i) { s += sA[i]; cA[i] = s; }
  }
  __syncthreads();
  if (t < CHK) {
    dec[t] = expf(cA[CHK - 1] - cA[t]);
    cumA[((size_t)(b * HH + h) * NC + c) * CHK + t] = cA[t];
  }
  // stage x*dt chunk [64][64]
#pragma unroll
  for (int i = 0; i < 16; ++i) {
    int f = t + i * 256;
    int l = f >> 6, p = f & 63;
    xds[l][p] = b2f(xsp[(size_t)(row0 + l) * DIN + h * PP + p]) * sdt[l];
  }
  // decay-masked G
#pragma unroll
  for (int i = 0; i < 16; ++i) {
    int f = t + i * 256;
    int l = f >> 6, s = f & 63;
    float g = G[((size_t)(b * NC + c) * CHK + l) * CHK + s];
    un[l * 65 + s] = (s <= l) ? g * expf(cA[l] - cA[s]) : 0.f;
  }
  __syncthreads();
  // Y_diag[l][p] = sum_s GM[l][s] * xds[s][p]
  {
    const int p0 = (t & 15) * 4, l0 = (t >> 4) * 4;
    float acc[4][4] = {};
    for (int s = 0; s < CHK; ++s) {
      float4 xv = *(const float4*)&xds[s][p0];
#pragma unroll
      for (int v = 0; v < 4; ++v) {
        float g = un[(l0 + v) * 65 + s];
        acc[v][0] += g * xv.x; acc[v][1] += g * xv.y;
        acc[v][2] += g * xv.z; acc[v][3] += g * xv.w;
      }
    }
#pragma unroll
    for (int v = 0; v < 4; ++v) {
      bf16* p = &y[(size_t)(row0 + l0 + v) * DIN + h * PP + p0];
      p[0] = f2b(acc[v][0]); p[1] = f2b(acc[v][1]);
      p[2] = f2b(acc[v][2]); p[3] = f2b(acc[v][3]);
    }
  }
  __syncthreads();
  // reload union as B chunk [64][128]
#pragma unroll
  for (int i = 0; i < 8; ++i) {
    int f = t + i * 256;
    int l = f >> 5, n4 = f & 31;
    *(float4*)&un[l * NSD + n4 * 4] =
        *(const float4*)&Bm[(size_t)(row0 + l) * NSD + n4 * 4];
  }
  __syncthreads();
  // states[p][n] = sum_l xds[l][p] * dec[l] * B[l][n]
  {
    const int n0 = (t & 31) * 4, p0 = (t >> 5) * 8;
    float acc[8][4] = {};
    for (int l = 0; l < CHK; ++l) {
      float4 bv = *(const float4*)&un[l * NSD + n0];
      float d = dec[l];
      float4 xa = *(const float4*)&xds[l][p0];
      float4 xb = *(const float4*)&xds[l][p0 + 4];
      float xv[8] = {xa.x, xa.y, xa.z, xa.w, xb.x, xb.y, xb.z, xb.w};
#pragma unroll
      for (int jp = 0; jp < 8; ++jp) {
        float xdc = xv[jp] * d;
        acc[jp][0] += xdc * bv.x; acc[jp][1] += xdc * bv.y;
        acc[jp][2] += xdc * bv.z; acc[jp][3] += xdc * bv.w;
      }
    }
    size_t sb = ((size_t)(b * NC + c) * HH + h) * (PP * NSD);
#pragma unroll
    for (int jp = 0; jp < 8; ++jp) {
      bf16* p = &states[sb + (size_t)(p0 + jp) * NSD + n0];
      p[0] = f2b(acc[jp][0]); p[1] = f2b(acc[jp][1]);
      p[2] = f2b(acc[jp][2]); p[3] = f2b(acc[jp][3]);
    }
  }
}

// ---------------------------------------------------------------------------
// Inter-chunk sequential scan, in place (bf16 storage, fp32 carry).
// ---------------------------------------------------------------------------
__global__ __launch_bounds__(256) void scan(bf16* __restrict__ states,
                                            const float* __restrict__ cumA) {
  const int q = blockIdx.x, h = blockIdx.y, b = blockIdx.z;
  const int t = threadIdx.x;
  float S[8] = {};
  for (int c = 0; c < NC; ++c) {
    float tot = expf(cumA[((size_t)(b * HH + h) * NC + c) * CHK + CHK - 1]);
    size_t base = ((size_t)(b * NC + c) * HH + h) * (PP * NSD) + q * 2048 + t;
#pragma unroll
    for (int i = 0; i < 8; ++i) {
      float cs = b2f(states[base + i * 256]);
      states[base + i * 256] = f2b(S[i]);
      S[i] = S[i] * tot + cs;
    }
  }
}

// ---------------------------------------------------------------------------
// Y_off[l][p] = dot(C[l,:], S[p,:]) * exp(cA[l]);  y += Y_off + xs*D.
// ---------------------------------------------------------------------------
__global__ __launch_bounds__(256) void yoff(
    const float* __restrict__ Cm, const bf16* __restrict__ states,
    const float* __restrict__ cumA, const bf16* __restrict__ xs,
    const float* __restrict__ Dp, bf16* __restrict__ y) {
  const int h = blockIdx.x, c = blockIdx.y, b = blockIdx.z;
  const int row0 = (b * NC + c) * CHK;
  __shared__ float Csh[CHK][67];
  __shared__ float Ssh[PP][67];
  __shared__ float dec[CHK];
  const int t = threadIdx.x;
  if (t < CHK) dec[t] = expf(cumA[((size_t)(b * HH + h) * NC + c) * CHK + t]);
  const float Dh = Dp[h];
  const size_t sbase = ((size_t)(b * NC + c) * HH + h) * (PP * NSD);
  float acc[16] = {};
  for (int nh = 0; nh < 2; ++nh) {
#pragma unroll
    for (int i = 0; i < 16; ++i) {
      int f = t + i * 256;
      int r = f >> 6, j = f & 63;
      Csh[r][j] = Cm[(size_t)(row0 + r) * NSD + nh * 64 + j];
      Ssh[r][j] = b2f(states[sbase + (size_t)r * NSD + nh * 64 + j]);
    }
    __syncthreads();
    const int p = t & 63, l0 = (t >> 6) * 16;
    for (int n = 0; n < 64; ++n) {
      float sv = Ssh[p][n];
#pragma unroll
      for (int j = 0; j < 16; ++j) acc[j] += Csh[l0 + j][n] * sv;
    }
    __syncthreads();
  }
  const int p = t & 63, l0 = (t >> 6) * 16;
#pragma unroll
  for (int j = 0; j < 16; ++j) {
    int row = row0 + l0 + j;
    size_t idx = (size_t)row * DIN + h * PP + p;
    y[idx] = f2b(b2f(y[idx]) + acc[j] * dec[l0 + j] + b2f(xs[idx]) * Dh);
  }
}

// ---------------------------------------------------------------------------
// yz = y * silu(z); RMS-normalize over d_inner; scale; bf16 out.
// ---------------------------------------------------------------------------
__global__ __launch_bounds__(256) void gatenorm(const bf16* __restrict__ y,
                                                const bf16* __restrict__ zb,
                                                const float* __restrict__ nsc,
                                                bf16* __restrict__ outn) {
  const int row = blockIdx.x, t = threadIdx.x;
  float v[8];
  float ss = 0.f;
#pragma unroll
  for (int i = 0; i < 8; ++i) {
    int ch = t + i * 256;
    float z  = b2f(zb[(size_t)row * DIN + ch]);
    float yv = b2f(y[(size_t)row * DIN + ch]);
    float g  = yv * z / (1.f + expf(-z));
    v[i] = g;
    ss += g * g;
  }
#pragma unroll
  for (int off = 32; off > 0; off >>= 1) ss += __shfl_down(ss, off, 64);
  __shared__ float red[4];
  if ((t & 63) == 0) red[t >> 6] = ss;
  __syncthreads();
  float tot = red[0] + red[1] + red[2] + red[3];
  float r = rsqrtf(tot * (1.f / DIN) + 1e-6f);
#pragma unroll
  for (int i = 0; i < 8; ++i) {
    int ch = t + i * 256;
    outn[(size_t)row * DIN + ch] = f2b(v[i] * r * nsc[ch]);
  }
}

// ---------------------------------------------------------------------------
extern "C" void kernel_launch(void* const* d_in, const int* in_sizes, int n_in,
                              void* d_out, int out_size, void* d_ws, size_t ws_size,
                              hipStream_t stream) {
  const float* x     = (const float*)d_in[0];
  const float* inw   = (const float*)d_in[1];
  const float* convw = (const float*)d_in[2];
  const float* convb = (const float*)d_in[3];
  const float* dtb   = (const float*)d_in[4];
  const float* alog  = (const float*)d_in[5];
  const float* Dp    = (const float*)d_in[6];
  const float* nsc   = (const float*)d_in[7];
  const float* outw  = (const float*)d_in[8];
  float* out = (float*)d_out;

  // workspace layout — ~178 MB total (bf16 intermediates, aliased reuse)
  char* p = (char*)d_ws;
  bf16*  zb     = (bf16*)p;  p += (size_t)ROWS * DIN * 2;          //  33.55 MB
  bf16*  xbcb   = (bf16*)p;  p += (size_t)ROWS * CONVD * 2;        //  37.75 MB
  bf16*  y      = xbcb;      // reuse: conv consumes xbcb before y is written
  float* dtraw  = (float*)p; p += (size_t)ROWS * HH * 4;           //   1.05 MB
  bf16*  xs     = (bf16*)p;  p += (size_t)ROWS * DIN * 2;          //  33.55 MB
  bf16*  states = (bf16*)p;  p += (size_t)BB * NC * HH * PP * NSD * 2; // 67.1 MB
  bf16*  normb  = states;    // reuse: yoff consumes states before norm written
  float* Bm     = (float*)p; p += (size_t)ROWS * NSD * 4;          //   4.19 MB
  float* Cm     = (float*)p; p += (size_t)ROWS * NSD * 4;          //   4.19 MB
  float* dtv    = (float*)p; p += (size_t)ROWS * HH * 4;           //   1.05 MB
  float* dtA    = (float*)p; p += (size_t)ROWS * HH * 4;           //   1.05 MB
  float* cumA   = (float*)p; p += (size_t)BB * HH * NC * CHK * 4;  //   1.05 MB
  float* G      = (float*)p; p += (size_t)BB * NC * CHK * CHK * 4; //   2.10 MB

  // 1. in_proj GEMM (split outputs)
  gemm_inproj<<<dim3((DPROJ + 63) / 64, ROWS / 64), 256, 0, stream>>>(
      x, inw, zb, xbcb, dtraw);
  // 2. conv + activations + splits
  conv_act<<<ROWS, 256, 0, stream>>>(xbcb, dtraw, convw, convb, dtb, alog,
                                     xs, Bm, Cm, dtv, dtA);
  // 3. G = C B^T per chunk
  gmat<<<dim3(2, NC, BB), 256, 0, stream>>>(Bm, Cm, G);
  // 4. Y_diag + chunk states per (b,c,h)  (y overwrites xbcb region)
  ssd_chunk<<<dim3(HH, NC, BB), 256, 0, stream>>>(G, xs, Bm, dtv, dtA,
                                                  y, states, cumA);
  // 5. inter-chunk scan (in place)
  scan<<<dim3(4, HH, BB), 256, 0, stream>>>(states, cumA);
  // 6. Y_off + D-term
  yoff<<<dim3(HH, NC, BB), 256, 0, stream>>>(Cm, states, cumA, xs, Dp, y);
  // 7. gate + RMSNorm (normed overwrites states region)
  gatenorm<<<ROWS, 256, 0, stream>>>(y, zb, nsc, normb);
  // 8. out_proj GEMM
  gemm_out<<<dim3(DM / 64, ROWS / 64), 256, 0, stream>>>(normb, outw, out);

  (void)in_sizes; (void)n_in; (void)out_size; (void)ws_size;
}

// Round 3
// 582.173 us; speedup vs baseline: 3.1037x; 3.1037x over previous
//
#include <hip/hip_runtime.h>
#include <hip/hip_bf16.h>
#include <math.h>

typedef __hip_bfloat16 bf16;
typedef __attribute__((ext_vector_type(8))) short short8;
typedef __attribute__((ext_vector_type(4))) float f32x4;

constexpr int BB    = 2;      // batch
constexpr int LL    = 4096;   // seq len
constexpr int DM    = 1024;   // d_model
constexpr int DIN   = 2048;   // d_inner
constexpr int HH    = 32;     // n_heads
constexpr int PP    = 64;     // head_dim
constexpr int NSD   = 128;    // d_state
constexpr int CONVD = 2304;   // d_inner + 2*d_state
constexpr int DPROJ = 4384;   // 2*d_inner + 2*d_state + n_heads
constexpr int NPAD  = 4480;   // DPROJ padded to 35*128
constexpr int CHK   = 64;     // chunk size
constexpr int NC    = 64;     // chunks per batch (L/CHK)
constexpr int ROWS  = BB * LL; // 8192

__device__ __forceinline__ float b2f(bf16 v) { return __bfloat162float(v); }
__device__ __forceinline__ bf16  f2b(float f) { return __float2bfloat16(f); }

// ---------------------------------------------------------------------------
// fp32 -> bf16 elementwise (x input for in_proj GEMM). 4 elems/thread.
// ---------------------------------------------------------------------------
__global__ __launch_bounds__(256) void convert_bf16(const float* __restrict__ in,
                                                    bf16* __restrict__ outp, int n4) {
  int i = blockIdx.x * 256 + threadIdx.x;
  if (i >= n4) return;
  float4 v = *(const float4*)&in[(size_t)i * 4];
  bf16* p = &outp[(size_t)i * 4];
  p[0] = f2b(v.x); p[1] = f2b(v.y); p[2] = f2b(v.z); p[3] = f2b(v.w);
}

// ---------------------------------------------------------------------------
// Transpose + convert: W fp32 [K][N] row-major -> Bt bf16 [Npad][K] row-major
// (k-contiguous per output row; rows n>=N zero-filled).
// ---------------------------------------------------------------------------
__global__ __launch_bounds__(256) void transpose_w(const float* __restrict__ W,
                                                   bf16* __restrict__ Bt,
                                                   int K, int N) {
  __shared__ float Tl[32][33];
  const int n0 = blockIdx.x * 32, k0 = blockIdx.y * 32;
  const int t = threadIdx.x;
  {
    const int kk = t >> 3, nn4 = (t & 7) * 4;
#pragma unroll
    for (int j = 0; j < 4; ++j) {
      int n = n0 + nn4 + j;
      Tl[kk][nn4 + j] = (n < N) ? W[(size_t)(k0 + kk) * N + n] : 0.f;
    }
  }
  __syncthreads();
  {
    const int nn = t >> 3, kk4 = (t & 7) * 4;
#pragma unroll
    for (int j = 0; j < 4; ++j)
      Bt[(size_t)(n0 + nn) * K + k0 + kk4 + j] = f2b(Tl[kk4 + j][nn]);
  }
}

// ---------------------------------------------------------------------------
// bf16 MFMA GEMM, 128x128 tile, BK=32, 4 waves (2x2), 4x4 16x16x32 tiles/wave.
// A bf16 [M][K] row-major; Bt bf16 [Npad][K] row-major (B transposed).
// XOR slot-swizzle (s + (row>>1))&3 on 16B slots: 2-way LDS access (free).
// MODE 0: split store zb/xbcb/dtraw (in_proj). MODE 1: fp32 C (out_proj).
// ---------------------------------------------------------------------------
template <int MODE>
__global__ __launch_bounds__(256) void gemm_mfma(
    const short* __restrict__ A, const short* __restrict__ Bt, int K,
    bf16* __restrict__ zb, bf16* __restrict__ xbcb,
    float* __restrict__ dtraw, float* __restrict__ Cout) {
  __shared__ short Asl[128 * 32];
  __shared__ short Bsl[128 * 32];
  const int t = threadIdx.x;
  const int l = t & 63;
  const int w = t >> 6;
  const int wr = w >> 1, wc = w & 1;
  const int m0 = blockIdx.y * 128;
  const int n0 = blockIdx.x * 128;
  f32x4 acc[4][4] = {};

  for (int k0 = 0; k0 < K; k0 += 32) {
#pragma unroll
    for (int i = 0; i < 2; ++i) {
      int f = t + i * 256;         // 0..511
      int row = f >> 2, s = f & 3; // tile row, logical 16B slot
      int s2 = (s + (row >> 1)) & 3;
      uint4 va = *(const uint4*)&A[(size_t)(m0 + row) * K + k0 + s * 8];
      *(uint4*)&Asl[row * 32 + s2 * 8] = va;
      uint4 vb = *(const uint4*)&Bt[(size_t)(n0 + row) * K + k0 + s * 8];
      *(uint4*)&Bsl[row * 32 + s2 * 8] = vb;
    }
    __syncthreads();
    short8 af[4], bg[4];
#pragma unroll
    for (int i = 0; i < 4; ++i) {
      int ar = wr * 64 + i * 16 + (l & 15);
      int as = ((l >> 4) + (ar >> 1)) & 3;
      af[i] = *(const short8*)&Asl[ar * 32 + as * 8];
      int br = wc * 64 + i * 16 + (l & 15);
      int bs = ((l >> 4) + (br >> 1)) & 3;
      bg[i] = *(const short8*)&Bsl[br * 32 + bs * 8];
    }
#pragma unroll
    for (int i = 0; i < 4; ++i)
#pragma unroll
      for (int j = 0; j < 4; ++j)
        acc[i][j] = __builtin_amdgcn_mfma_f32_16x16x32_bf16(af[i], bg[j],
                                                            acc[i][j], 0, 0, 0);
    __syncthreads();
  }
  // epilogue: D col = lane&15, row = (lane>>4)*4 + q
#pragma unroll
  for (int i = 0; i < 4; ++i) {
#pragma unroll
    for (int j = 0; j < 4; ++j) {
      int gcol = n0 + wc * 64 + j * 16 + (l & 15);
      int grow0 = m0 + wr * 64 + i * 16 + (l >> 4) * 4;
#pragma unroll
      for (int q = 0; q < 4; ++q) {
        float v = acc[i][j][q];
        int grow = grow0 + q;
        if constexpr (MODE == 0) {
          if (gcol < DIN) {
            zb[(size_t)grow * DIN + gcol] = f2b(v);
          } else if (gcol < DIN + CONVD) {
            xbcb[(size_t)grow * CONVD + (gcol - DIN)] = f2b(v);
          } else if (gcol < DPROJ) {
            dtraw[(size_t)grow * HH + (gcol - DIN - CONVD)] = v;
          }
        } else {
          Cout[(size_t)grow * DM + gcol] = v;
        }
      }
    }
  }
}

// ---------------------------------------------------------------------------
// Depthwise causal conv1d (k=4) + bias + silu + splits; dt softplus; dtA.
// ---------------------------------------------------------------------------
__global__ __launch_bounds__(256) void conv_act(
    const bf16* __restrict__ xbc, const float* __restrict__ dtraw,
    const float* __restrict__ convw, const float* __restrict__ convb,
    const float* __restrict__ dtb, const float* __restrict__ alog,
    bf16* __restrict__ xs, float* __restrict__ Bm, float* __restrict__ Cm,
    float* __restrict__ dtv, float* __restrict__ dtA) {
  const int row = blockIdx.x;
  const int l   = row & (LL - 1);
  const int t   = threadIdx.x;
  if (t < HH) {
    float raw = dtraw[(size_t)row * HH + t] + dtb[t];
    float dt  = (raw > 20.f) ? raw : log1pf(expf(raw));
    dtv[(size_t)row * HH + t] = dt;
    dtA[(size_t)row * HH + t] = -expf(alog[t]) * dt;
  }
  for (int ch = t; ch < CONVD; ch += 256) {
    float acc = convb[ch];
#pragma unroll
    for (int k = 0; k < 4; ++k) {
      int ll = l - 3 + k;
      if (ll >= 0)
        acc += b2f(xbc[(size_t)(row - 3 + k) * CONVD + ch]) * convw[k * CONVD + ch];
    }
    float s = acc / (1.f + expf(-acc)); // silu
    if (ch < DIN) {
      xs[(size_t)row * DIN + ch] = f2b(s);
    } else if (ch < DIN + NSD) {
      Bm[(size_t)row * NSD + (ch - DIN)] = s;
    } else {
      Cm[(size_t)row * NSD + (ch - DIN - NSD)] = s;
    }
  }
}

// ---------------------------------------------------------------------------
// G[b,c,l,s] = dot(C[l,:], B[s,:]) over d_state (head-independent).
// ---------------------------------------------------------------------------
__global__ __launch_bounds__(256) void gmat(const float* __restrict__ Bm,
                                            const float* __restrict__ Cm,
                                            float* __restrict__ G) {
  const int sh = blockIdx.x;
  const int c = blockIdx.y, b = blockIdx.z;
  const int row0 = (b * NC + c) * CHK;
  __shared__ float CshT[NSD][CHK + 1];
  __shared__ float BshT[NSD][33];
  const int t = threadIdx.x;
#pragma unroll
  for (int i = 0; i < 8; ++i) {
    int f = t + i * 256;
    int l = f >> 5, n4 = f & 31;
    float4 v = *(const float4*)&Cm[(size_t)(row0 + l) * NSD + n4 * 4];
    CshT[n4 * 4 + 0][l] = v.x; CshT[n4 * 4 + 1][l] = v.y;
    CshT[n4 * 4 + 2][l] = v.z; CshT[n4 * 4 + 3][l] = v.w;
  }
#pragma unroll
  for (int i = 0; i < 4; ++i) {
    int f = t + i * 256;
    int s = f >> 5, n4 = f & 31;
    float4 v = *(const float4*)&Bm[(size_t)(row0 + sh * 32 + s) * NSD + n4 * 4];
    BshT[n4 * 4 + 0][s] = v.x; BshT[n4 * 4 + 1][s] = v.y;
    BshT[n4 * 4 + 2][s] = v.z; BshT[n4 * 4 + 3][s] = v.w;
  }
  __syncthreads();
  const int l  = t & 63;
  const int s0 = (t >> 6) * 8;
  float acc[8] = {};
  for (int n = 0; n < NSD; ++n) {
    float cv = CshT[n][l];
#pragma unroll
    for (int j = 0; j < 8; ++j) acc[j] += cv * BshT[n][s0 + j];
  }
  float* gp = &G[((size_t)(b * NC + c) * CHK + l) * CHK + sh * 32 + s0];
  *(float4*)&gp[0] = make_float4(acc[0], acc[1], acc[2], acc[3]);
  *(float4*)&gp[4] = make_float4(acc[4], acc[5], acc[6], acc[7]);
}

// ---------------------------------------------------------------------------
// Per (b,c,h): cumsum(dtA), decay-masked G -> Y_diag (bf16), chunk states (bf16).
// ---------------------------------------------------------------------------
__global__ __launch_bounds__(256) void ssd_chunk(
    const float* __restrict__ G, const bf16* __restrict__ xsp,
    const float* __restrict__ Bm, const float* __restrict__ dtv,
    const float* __restrict__ dtA,
    bf16* __restrict__ y, bf16* __restrict__ states, float* __restrict__ cumA) {
  const int h = blockIdx.x, c = blockIdx.y, b = blockIdx.z;
  const int row0 = (b * NC + c) * CHK;
  __shared__ float un[CHK * NSD];      // GM (stride 65) then B chunk (stride 128)
  __shared__ float xds[CHK][CHK + 4];
  __shared__ float sA[CHK], cA[CHK], dec[CHK], sdt[CHK];
  const int t = threadIdx.x;
  if (t < CHK) {
    sA[t]  = dtA[(size_t)(row0 + t) * HH + h];
    sdt[t] = dtv[(size_t)(row0 + t) * HH + h];
  }
  __syncthreads();
  if (t == 0) {
    float s = 0.f;
    for (int i = 0; i < CHK; ++i) { s += sA[i]; cA[i] = s; }
  }
  __syncthreads();
  if (t < CHK) {
    dec[t] = expf(cA[CHK - 1] - cA[t]);
    cumA[((size_t)(b * HH + h) * NC + c) * CHK + t] = cA[t];
  }
  // stage x*dt chunk [64][64]
#pragma unroll
  for (int i = 0; i < 16; ++i) {
    int f = t + i * 256;
    int l = f >> 6, p = f & 63;
    xds[l][p] = b2f(xsp[(size_t)(row0 + l) * DIN + h * PP + p]) * sdt[l];
  }
  // decay-masked G
#pragma unroll
  for (int i = 0; i < 16; ++i) {
    int f = t + i * 256;
    int l = f >> 6, s = f & 63;
    float g = G[((size_t)(b * NC + c) * CHK + l) * CHK + s];
    un[l * 65 + s] = (s <= l) ? g * expf(cA[l] - cA[s]) : 0.f;
  }
  __syncthreads();
  // Y_diag[l][p] = sum_s GM[l][s] * xds[s][p]
  {
    const int p0 = (t & 15) * 4, l0 = (t >> 4) * 4;
    float acc[4][4] = {};
    for (int s = 0; s < CHK; ++s) {
      float4 xv = *(const float4*)&xds[s][p0];
#pragma unroll
      for (int v = 0; v < 4; ++v) {
        float g = un[(l0 + v) * 65 + s];
        acc[v][0] += g * xv.x; acc[v][1] += g * xv.y;
        acc[v][2] += g * xv.z; acc[v][3] += g * xv.w;
      }
    }
#pragma unroll
    for (int v = 0; v < 4; ++v) {
      bf16* p = &y[(size_t)(row0 + l0 + v) * DIN + h * PP + p0];
      p[0] = f2b(acc[v][0]); p[1] = f2b(acc[v][1]);
      p[2] = f2b(acc[v][2]); p[3] = f2b(acc[v][3]);
    }
  }
  __syncthreads();
  // reload union as B chunk [64][128]
#pragma unroll
  for (int i = 0; i < 8; ++i) {
    int f = t + i * 256;
    int l = f >> 5, n4 = f & 31;
    *(float4*)&un[l * NSD + n4 * 4] =
        *(const float4*)&Bm[(size_t)(row0 + l) * NSD + n4 * 4];
  }
  __syncthreads();
  // states[p][n] = sum_l xds[l][p] * dec[l] * B[l][n]
  {
    const int n0 = (t & 31) * 4, p0 = (t >> 5) * 8;
    float acc[8][4] = {};
    for (int l = 0; l < CHK; ++l) {
      float4 bv = *(const float4*)&un[l * NSD + n0];
      float d = dec[l];
      float4 xa = *(const float4*)&xds[l][p0];
      float4 xb = *(const float4*)&xds[l][p0 + 4];
      float xv[8] = {xa.x, xa.y, xa.z, xa.w, xb.x, xb.y, xb.z, xb.w};
#pragma unroll
      for (int jp = 0; jp < 8; ++jp) {
        float xdc = xv[jp] * d;
        acc[jp][0] += xdc * bv.x; acc[jp][1] += xdc * bv.y;
        acc[jp][2] += xdc * bv.z; acc[jp][3] += xdc * bv.w;
      }
    }
    size_t sb = ((size_t)(b * NC + c) * HH + h) * (PP * NSD);
#pragma unroll
    for (int jp = 0; jp < 8; ++jp) {
      bf16* p = &states[sb + (size_t)(p0 + jp) * NSD + n0];
      p[0] = f2b(acc[jp][0]); p[1] = f2b(acc[jp][1]);
      p[2] = f2b(acc[jp][2]); p[3] = f2b(acc[jp][3]);
    }
  }
}

// ---------------------------------------------------------------------------
// Inter-chunk sequential scan, in place (bf16 storage, fp32 carry).
// ---------------------------------------------------------------------------
__global__ __launch_bounds__(256) void scan(bf16* __restrict__ states,
                                            const float* __restrict__ cumA) {
  const int q = blockIdx.x, h = blockIdx.y, b = blockIdx.z;
  const int t = threadIdx.x;
  float S[8] = {};
  for (int c = 0; c < NC; ++c) {
    float tot = expf(cumA[((size_t)(b * HH + h) * NC + c) * CHK + CHK - 1]);
    size_t base = ((size_t)(b * NC + c) * HH + h) * (PP * NSD) + q * 2048 + t;
#pragma unroll
    for (int i = 0; i < 8; ++i) {
      float cs = b2f(states[base + i * 256]);
      states[base + i * 256] = f2b(S[i]);
      S[i] = S[i] * tot + cs;
    }
  }
}

// ---------------------------------------------------------------------------
// Y_off[l][p] = dot(C[l,:], S[p,:]) * exp(cA[l]);  y += Y_off + xs*D.
// ---------------------------------------------------------------------------
__global__ __launch_bounds__(256) void yoff(
    const float* __restrict__ Cm, const bf16* __restrict__ states,
    const float* __restrict__ cumA, const bf16* __restrict__ xs,
    const float* __restrict__ Dp, bf16* __restrict__ y) {
  const int h = blockIdx.x, c = blockIdx.y, b = blockIdx.z;
  const int row0 = (b * NC + c) * CHK;
  __shared__ float Csh[CHK][67];
  __shared__ float Ssh[PP][67];
  __shared__ float dec[CHK];
  const int t = threadIdx.x;
  if (t < CHK) dec[t] = expf(cumA[((size_t)(b * HH + h) * NC + c) * CHK + t]);
  const float Dh = Dp[h];
  const size_t sbase = ((size_t)(b * NC + c) * HH + h) * (PP * NSD);
  float acc[16] = {};
  for (int nh = 0; nh < 2; ++nh) {
#pragma unroll
    for (int i = 0; i < 16; ++i) {
      int f = t + i * 256;
      int r = f >> 6, j = f & 63;
      Csh[r][j] = Cm[(size_t)(row0 + r) * NSD + nh * 64 + j];
      Ssh[r][j] = b2f(states[sbase + (size_t)r * NSD + nh * 64 + j]);
    }
    __syncthreads();
    const int p = t & 63, l0 = (t >> 6) * 16;
    for (int n = 0; n < 64; ++n) {
      float sv = Ssh[p][n];
#pragma unroll
      for (int j = 0; j < 16; ++j) acc[j] += Csh[l0 + j][n] * sv;
    }
    __syncthreads();
  }
  const int p = t & 63, l0 = (t >> 6) * 16;
#pragma unroll
  for (int j = 0; j < 16; ++j) {
    int row = row0 + l0 + j;
    size_t idx = (size_t)row * DIN + h * PP + p;
    y[idx] = f2b(b2f(y[idx]) + acc[j] * dec[l0 + j] + b2f(xs[idx]) * Dh);
  }
}

// ---------------------------------------------------------------------------
// yz = y * silu(z); RMS-normalize over d_inner; scale; bf16 out.
// ---------------------------------------------------------------------------
__global__ __launch_bounds__(256) void gatenorm(const bf16* __restrict__ y,
                                                const bf16* __restrict__ zb,
                                                const float* __restrict__ nsc,
                                                bf16* __restrict__ outn) {
  const int row = blockIdx.x, t = threadIdx.x;
  float v[8];
  float ss = 0.f;
#pragma unroll
  for (int i = 0; i < 8; ++i) {
    int ch = t + i * 256;
    float z  = b2f(zb[(size_t)row * DIN + ch]);
    float yv = b2f(y[(size_t)row * DIN + ch]);
    float g  = yv * z / (1.f + expf(-z));
    v[i] = g;
    ss += g * g;
  }
#pragma unroll
  for (int off = 32; off > 0; off >>= 1) ss += __shfl_down(ss, off, 64);
  __shared__ float red[4];
  if ((t & 63) == 0) red[t >> 6] = ss;
  __syncthreads();
  float tot = red[0] + red[1] + red[2] + red[3];
  float r = rsqrtf(tot * (1.f / DIN) + 1e-6f);
#pragma unroll
  for (int i = 0; i < 8; ++i) {
    int ch = t + i * 256;
    outn[(size_t)row * DIN + ch] = f2b(v[i] * r * nsc[ch]);
  }
}

// ---------------------------------------------------------------------------
extern "C" void kernel_launch(void* const* d_in, const int* in_sizes, int n_in,
                              void* d_out, int out_size, void* d_ws, size_t ws_size,
                              hipStream_t stream) {
  const float* x     = (const float*)d_in[0];
  const float* inw   = (const float*)d_in[1];
  const float* convw = (const float*)d_in[2];
  const float* convb = (const float*)d_in[3];
  const float* dtb   = (const float*)d_in[4];
  const float* alog  = (const float*)d_in[5];
  const float* Dp    = (const float*)d_in[6];
  const float* nsc   = (const float*)d_in[7];
  const float* outw  = (const float*)d_in[8];
  float* out = (float*)d_out;

  // workspace layout — ~213 MB total (bf16 intermediates, aliased reuse)
  char* p = (char*)d_ws;
  bf16*  zb     = (bf16*)p;  p += (size_t)ROWS * DIN * 2;          //  33.6 MB
  bf16*  xbcb   = (bf16*)p;  p += (size_t)ROWS * CONVD * 2;        //  37.7 MB
  bf16*  y      = xbcb;      // reuse: conv consumes xbcb before y is written
  float* dtraw  = (float*)p; p += (size_t)ROWS * HH * 4;           //   1.0 MB
  bf16*  xs     = (bf16*)p;  p += (size_t)ROWS * DIN * 2;          //  33.6 MB
  bf16*  states = (bf16*)p;  p += (size_t)BB * NC * HH * PP * NSD * 2; // 67.1 MB
  bf16*  normb  = states;    // reuse: yoff consumes states before norm written
  float* Bm     = (float*)p; p += (size_t)ROWS * NSD * 4;          //   4.2 MB
  float* Cm     = (float*)p; p += (size_t)ROWS * NSD * 4;          //   4.2 MB
  float* dtv    = (float*)p; p += (size_t)ROWS * HH * 4;           //   1.0 MB
  float* dtA    = (float*)p; p += (size_t)ROWS * HH * 4;           //   1.0 MB
  float* cumA   = (float*)p; p += (size_t)BB * HH * NC * CHK * 4;  //   1.0 MB
  float* G      = (float*)p; p += (size_t)BB * NC * CHK * CHK * 4; //   2.1 MB
  bf16*  xb     = (bf16*)p;  p += (size_t)ROWS * DM * 2;           //  16.8 MB
  bf16*  BtIn   = (bf16*)p;  p += (size_t)NPAD * DM * 2;           //   9.2 MB
  bf16*  BtOut  = xb;        // reuse: xb dead after in_proj GEMM (4.2 MB)

  // 0a. x -> bf16
  convert_bf16<<<(ROWS * DM / 4 + 255) / 256, 256, 0, stream>>>(x, xb, ROWS * DM / 4);
  // 0b. in_proj_w [DM][DPROJ] -> BtIn bf16 [NPAD][DM]
  transpose_w<<<dim3(NPAD / 32, DM / 32), 256, 0, stream>>>(inw, BtIn, DM, DPROJ);
  // 1. in_proj GEMM (MFMA, split outputs)
  gemm_mfma<0><<<dim3(NPAD / 128, ROWS / 128), 256, 0, stream>>>(
      (const short*)xb, (const short*)BtIn, DM, zb, xbcb, dtraw, nullptr);
  // 0c. out_proj_w [DIN][DM] -> BtOut bf16 [DM][DIN]  (into dead xb region)
  transpose_w<<<dim3(DM / 32, DIN / 32), 256, 0, stream>>>(outw, BtOut, DIN, DM);
  // 2. conv + activations + splits
  conv_act<<<ROWS, 256, 0, stream>>>(xbcb, dtraw, convw, convb, dtb, alog,
                                     xs, Bm, Cm, dtv, dtA);
  // 3. G = C B^T per chunk
  gmat<<<dim3(2, NC, BB), 256, 0, stream>>>(Bm, Cm, G);
  // 4. Y_diag + chunk states per (b,c,h)  (y overwrites xbcb region)
  ssd_chunk<<<dim3(HH, NC, BB), 256, 0, stream>>>(G, xs, Bm, dtv, dtA,
                                                  y, states, cumA);
  // 5. inter-chunk scan (in place)
  scan<<<dim3(4, HH, BB), 256, 0, stream>>>(states, cumA);
  // 6. Y_off + D-term
  yoff<<<dim3(HH, NC, BB), 256, 0, stream>>>(Cm, states, cumA, xs, Dp, y);
  // 7. gate + RMSNorm (normed overwrites states region)
  gatenorm<<<ROWS, 256, 0, stream>>>(y, zb, nsc, normb);
  // 8. out_proj GEMM (MFMA, fp32 out)
  gemm_mfma<1><<<dim3(DM / 128, ROWS / 128), 256, 0, stream>>>(
      (const short*)normb, (const short*)BtOut, DIN, nullptr, nullptr, nullptr, out);

  (void)in_sizes; (void)n_in; (void)out_size; (void)ws_size;
}

// Round 4
// 384.712 us; speedup vs baseline: 4.6967x; 1.5133x over previous
//
#include <hip/hip_runtime.h>
#include <hip/hip_bf16.h>
#include <math.h>

typedef __hip_bfloat16 bf16;
typedef __attribute__((ext_vector_type(8))) short short8;
typedef __attribute__((ext_vector_type(4))) float f32x4;

constexpr int BB    = 2;      // batch
constexpr int LL    = 4096;   // seq len
constexpr int DM    = 1024;   // d_model
constexpr int DIN   = 2048;   // d_inner
constexpr int HH    = 32;     // n_heads
constexpr int PP    = 64;     // head_dim
constexpr int NSD   = 128;    // d_state
constexpr int CONVD = 2304;   // d_inner + 2*d_state
constexpr int DPROJ = 4384;   // 2*d_inner + 2*d_state + n_heads
constexpr int NPAD  = 4480;   // DPROJ padded to 35*128
constexpr int CHK   = 64;     // chunk size
constexpr int NC    = 64;     // chunks per batch (L/CHK)
constexpr int ROWS  = BB * LL; // 8192

__device__ __forceinline__ float b2f(bf16 v) { return __bfloat162float(v); }
__device__ __forceinline__ bf16  f2b(float f) { return __float2bfloat16(f); }
__device__ __forceinline__ short f2bs(float f) {
  bf16 b = f2b(f);
  return *reinterpret_cast<short*>(&b);
}

// ---------------------------------------------------------------------------
// fp32 -> bf16 elementwise (x input for in_proj GEMM). 4 elems/thread.
// ---------------------------------------------------------------------------
__global__ __launch_bounds__(256) void convert_bf16(const float* __restrict__ in,
                                                    bf16* __restrict__ outp, int n4) {
  int i = blockIdx.x * 256 + threadIdx.x;
  if (i >= n4) return;
  float4 v = *(const float4*)&in[(size_t)i * 4];
  bf16* p = &outp[(size_t)i * 4];
  p[0] = f2b(v.x); p[1] = f2b(v.y); p[2] = f2b(v.z); p[3] = f2b(v.w);
}

// ---------------------------------------------------------------------------
// Transpose + convert: W fp32 [K][N] row-major -> Bt bf16 [Npad][K] row-major.
// ---------------------------------------------------------------------------
__global__ __launch_bounds__(256) void transpose_w(const float* __restrict__ W,
                                                   bf16* __restrict__ Bt,
                                                   int K, int N) {
  __shared__ float Tl[32][33];
  const int n0 = blockIdx.x * 32, k0 = blockIdx.y * 32;
  const int t = threadIdx.x;
  {
    const int kk = t >> 3, nn4 = (t & 7) * 4;
#pragma unroll
    for (int j = 0; j < 4; ++j) {
      int n = n0 + nn4 + j;
      Tl[kk][nn4 + j] = (n < N) ? W[(size_t)(k0 + kk) * N + n] : 0.f;
    }
  }
  __syncthreads();
  {
    const int nn = t >> 3, kk4 = (t & 7) * 4;
#pragma unroll
    for (int j = 0; j < 4; ++j)
      Bt[(size_t)(n0 + nn) * K + k0 + kk4 + j] = f2b(Tl[kk4 + j][nn]);
  }
}

// ---------------------------------------------------------------------------
// bf16 MFMA GEMM, 128x128 tile, BK=32, 4 waves (2x2), 4x4 16x16x32 tiles/wave.
// MODE 0: split store zb/xbcb/dtraw (in_proj). MODE 1: fp32 C (out_proj).
// ---------------------------------------------------------------------------
template <int MODE>
__global__ __launch_bounds__(256) void gemm_mfma(
    const short* __restrict__ A, const short* __restrict__ Bt, int K,
    bf16* __restrict__ zb, bf16* __restrict__ xbcb,
    float* __restrict__ dtraw, float* __restrict__ Cout) {
  __shared__ short Asl[128 * 32];
  __shared__ short Bsl[128 * 32];
  const int t = threadIdx.x;
  const int l = t & 63;
  const int w = t >> 6;
  const int wr = w >> 1, wc = w & 1;
  const int m0 = blockIdx.y * 128;
  const int n0 = blockIdx.x * 128;
  f32x4 acc[4][4] = {};

  for (int k0 = 0; k0 < K; k0 += 32) {
#pragma unroll
    for (int i = 0; i < 2; ++i) {
      int f = t + i * 256;
      int row = f >> 2, s = f & 3;
      int s2 = (s + (row >> 1)) & 3;
      uint4 va = *(const uint4*)&A[(size_t)(m0 + row) * K + k0 + s * 8];
      *(uint4*)&Asl[row * 32 + s2 * 8] = va;
      uint4 vb = *(const uint4*)&Bt[(size_t)(n0 + row) * K + k0 + s * 8];
      *(uint4*)&Bsl[row * 32 + s2 * 8] = vb;
    }
    __syncthreads();
    short8 af[4], bg[4];
#pragma unroll
    for (int i = 0; i < 4; ++i) {
      int ar = wr * 64 + i * 16 + (l & 15);
      int as = ((l >> 4) + (ar >> 1)) & 3;
      af[i] = *(const short8*)&Asl[ar * 32 + as * 8];
      int br = wc * 64 + i * 16 + (l & 15);
      int bs = ((l >> 4) + (br >> 1)) & 3;
      bg[i] = *(const short8*)&Bsl[br * 32 + bs * 8];
    }
#pragma unroll
    for (int i = 0; i < 4; ++i)
#pragma unroll
      for (int j = 0; j < 4; ++j)
        acc[i][j] = __builtin_amdgcn_mfma_f32_16x16x32_bf16(af[i], bg[j],
                                                            acc[i][j], 0, 0, 0);
    __syncthreads();
  }
#pragma unroll
  for (int i = 0; i < 4; ++i) {
#pragma unroll
    for (int j = 0; j < 4; ++j) {
      int gcol = n0 + wc * 64 + j * 16 + (l & 15);
      int grow0 = m0 + wr * 64 + i * 16 + (l >> 4) * 4;
#pragma unroll
      for (int q = 0; q < 4; ++q) {
        float v = acc[i][j][q];
        int grow = grow0 + q;
        if constexpr (MODE == 0) {
          if (gcol < DIN) {
            zb[(size_t)grow * DIN + gcol] = f2b(v);
          } else if (gcol < DIN + CONVD) {
            xbcb[(size_t)grow * CONVD + (gcol - DIN)] = f2b(v);
          } else if (gcol < DPROJ) {
            dtraw[(size_t)grow * HH + (gcol - DIN - CONVD)] = v;
          }
        } else {
          Cout[(size_t)grow * DM + gcol] = v;
        }
      }
    }
  }
}

// ---------------------------------------------------------------------------
// Depthwise causal conv1d (k=4) + bias + silu + splits; dt softplus; dtA.
// 8 channels per thread, uint4 (8x bf16) loads/stores.
// ---------------------------------------------------------------------------
__global__ __launch_bounds__(256) void conv_act(
    const bf16* __restrict__ xbc, const float* __restrict__ dtraw,
    const float* __restrict__ convw, const float* __restrict__ convb,
    const float* __restrict__ dtb, const float* __restrict__ alog,
    bf16* __restrict__ xs, bf16* __restrict__ Bb, bf16* __restrict__ Cb,
    float* __restrict__ dtv, float* __restrict__ dtA) {
  const int row = blockIdx.x;
  const int l   = row & (LL - 1);
  const int t   = threadIdx.x;
  if (t < HH) {
    float raw = dtraw[(size_t)row * HH + t] + dtb[t];
    float dt  = (raw > 20.f) ? raw : log1pf(expf(raw));
    dtv[(size_t)row * HH + t] = dt;
    dtA[(size_t)row * HH + t] = -expf(alog[t]) * dt;
  }
  for (int ch = t * 8; ch < CONVD; ch += 2048) {
    float acc[8];
#pragma unroll
    for (int j = 0; j < 8; ++j) acc[j] = convb[ch + j];
#pragma unroll
    for (int k = 0; k < 4; ++k) {
      if (l - 3 + k >= 0) {
        uint4 v = *(const uint4*)&xbc[(size_t)(row - 3 + k) * CONVD + ch];
        const bf16* pv = (const bf16*)&v;
        const float* wp = &convw[k * CONVD + ch];
#pragma unroll
        for (int j = 0; j < 8; ++j) acc[j] += b2f(pv[j]) * wp[j];
      }
    }
    short8 sv;
#pragma unroll
    for (int j = 0; j < 8; ++j) {
      float s = acc[j] / (1.f + expf(-acc[j])); // silu
      sv[j] = f2bs(s);
    }
    if (ch < DIN) {
      *(short8*)&xs[(size_t)row * DIN + ch] = sv;
    } else if (ch < DIN + NSD) {
      *(short8*)&Bb[(size_t)row * NSD + (ch - DIN)] = sv;
    } else {
      *(short8*)&Cb[(size_t)row * NSD + (ch - DIN - NSD)] = sv;
    }
  }
}

// ---------------------------------------------------------------------------
// G[b,c,l,s] = dot(C[l,:], B[s,:]) — MFMA. One block per (b,c).
// A = Cb chunk [64 l][128 n] (k-contig), Bt = Bb chunk [64 s][128 n] (k-contig).
// ---------------------------------------------------------------------------
__global__ __launch_bounds__(256) void gmat(const bf16* __restrict__ Bb,
                                            const bf16* __restrict__ Cb,
                                            float* __restrict__ G) {
  const int c = blockIdx.x, b = blockIdx.y;
  const int row0 = (b * NC + c) * CHK;
  __shared__ short Csh[64][136];  // pad 8 shorts: row stride 272B (16B-mult)
  __shared__ short Bsh[64][136];
  const int t = threadIdx.x;
  const int lane = t & 63, w = t >> 6;
#pragma unroll
  for (int i = 0; i < 4; ++i) {
    int f = t + i * 256;        // 0..1023
    int rr = f >> 4, n0 = (f & 15) * 8;
    *(uint4*)&Csh[rr][n0] = *(const uint4*)&Cb[(size_t)(row0 + rr) * NSD + n0];
    *(uint4*)&Bsh[rr][n0] = *(const uint4*)&Bb[(size_t)(row0 + rr) * NSD + n0];
  }
  __syncthreads();
  f32x4 acc[4] = {};
  const int r = lane & 15, hi = lane >> 4;
#pragma unroll
  for (int kk = 0; kk < 4; ++kk) {
    short8 af = *(const short8*)&Csh[16 * w + r][kk * 32 + hi * 8];
#pragma unroll
    for (int j = 0; j < 4; ++j) {
      short8 bg = *(const short8*)&Bsh[16 * j + r][kk * 32 + hi * 8];
      acc[j] = __builtin_amdgcn_mfma_f32_16x16x32_bf16(af, bg, acc[j], 0, 0, 0);
    }
  }
#pragma unroll
  for (int j = 0; j < 4; ++j)
#pragma unroll
    for (int q = 0; q < 4; ++q) {
      int ll = 16 * w + hi * 4 + q, ss = 16 * j + r;
      G[((size_t)(b * NC + c) * CHK + ll) * CHK + ss] = acc[j][q];
    }
}

// ---------------------------------------------------------------------------
// Per (b,c,h): cumsum(dtA); Y_diag = GM @ xds (MFMA); states = xds^T·dec @ B
// (MFMA). GM = decay-masked G (bf16); xdsT staged transposed; dec folded in BdT.
// ---------------------------------------------------------------------------
__global__ __launch_bounds__(256) void ssd_chunk(
    const float* __restrict__ G, const bf16* __restrict__ xsp,
    const bf16* __restrict__ Bb, const float* __restrict__ dtv,
    const float* __restrict__ dtA,
    bf16* __restrict__ y, bf16* __restrict__ states, float* __restrict__ cumA) {
  const int h = blockIdx.x, c = blockIdx.y, b = blockIdx.z;
  const int row0 = (b * NC + c) * CHK;
  __shared__ short GMb[64][72];   // A for Y_diag: rows l, k=s contig
  __shared__ short xdsT[64][72];  // [p][l]: B for Y_diag (k=s), A for states (k=l)
  __shared__ short BdT[128][72];  // [n][l], dec folded: B for states
  __shared__ float sA[CHK], cA[CHK], dec[CHK], sdt[CHK];
  const int t = threadIdx.x;
  const int lane = t & 63, w = t >> 6;
  if (t < CHK) {
    sA[t]  = dtA[(size_t)(row0 + t) * HH + h];
    sdt[t] = dtv[(size_t)(row0 + t) * HH + h];
  }
  __syncthreads();
  if (t == 0) {
    float s = 0.f;
    for (int i = 0; i < CHK; ++i) { s += sA[i]; cA[i] = s; }
  }
  __syncthreads();
  if (t < CHK) {
    dec[t] = expf(cA[CHK - 1] - cA[t]);
    cumA[((size_t)(b * HH + h) * NC + c) * CHK + t] = cA[t];
  }
  // stage xdsT[p][l] = xs[row0+l][h*64+p] * dt[l]  (coalesced read, scatter write)
#pragma unroll
  for (int i = 0; i < 2; ++i) {
    int f = t + i * 256;          // 0..511
    int ll = f >> 3, p0 = (f & 7) * 8;
    uint4 v = *(const uint4*)&xsp[(size_t)(row0 + ll) * DIN + h * PP + p0];
    const bf16* pv = (const bf16*)&v;
    float dtl = sdt[ll];
#pragma unroll
    for (int j = 0; j < 8; ++j) xdsT[p0 + j][ll] = f2bs(b2f(pv[j]) * dtl);
  }
  // stage GM[l][s] = (s<=l) ? G*exp(cA[l]-cA[s]) : 0  (bf16)
#pragma unroll
  for (int i = 0; i < 4; ++i) {
    int f = t + i * 256;          // 0..1023
    int ll = f >> 4, s0 = (f & 15) * 4;
    float4 g = *(const float4*)&G[((size_t)(b * NC + c) * CHK + ll) * CHK + s0];
    float ca = cA[ll];
    GMb[ll][s0 + 0] = f2bs((s0 + 0 <= ll) ? g.x * expf(ca - cA[s0 + 0]) : 0.f);
    GMb[ll][s0 + 1] = f2bs((s0 + 1 <= ll) ? g.y * expf(ca - cA[s0 + 1]) : 0.f);
    GMb[ll][s0 + 2] = f2bs((s0 + 2 <= ll) ? g.z * expf(ca - cA[s0 + 2]) : 0.f);
    GMb[ll][s0 + 3] = f2bs((s0 + 3 <= ll) ? g.w * expf(ca - cA[s0 + 3]) : 0.f);
  }
  __syncthreads();
  // stage BdT[n][l] = B[row0+l][n] * dec[l]
#pragma unroll
  for (int i = 0; i < 4; ++i) {
    int f = t + i * 256;          // 0..1023
    int ll = f >> 4, n0 = (f & 15) * 8;
    uint4 v = *(const uint4*)&Bb[(size_t)(row0 + ll) * NSD + n0];
    const bf16* pv = (const bf16*)&v;
    float dl = dec[ll];
#pragma unroll
    for (int j = 0; j < 8; ++j) BdT[n0 + j][ll] = f2bs(b2f(pv[j]) * dl);
  }
  __syncthreads();
  const int r = lane & 15, hi = lane >> 4;
  // Y_diag: D[l][p], wave w owns l-strip [16w,16w+16)
  {
    f32x4 acc[4] = {};
#pragma unroll
    for (int kk = 0; kk < 2; ++kk) {
      short8 af = *(const short8*)&GMb[16 * w + r][kk * 32 + hi * 8];
#pragma unroll
      for (int j = 0; j < 4; ++j) {
        short8 bg = *(const short8*)&xdsT[16 * j + r][kk * 32 + hi * 8];
        acc[j] = __builtin_amdgcn_mfma_f32_16x16x32_bf16(af, bg, acc[j], 0, 0, 0);
      }
    }
#pragma unroll
    for (int j = 0; j < 4; ++j)
#pragma unroll
      for (int q = 0; q < 4; ++q) {
        int ll = 16 * w + hi * 4 + q, pp = 16 * j + r;
        y[(size_t)(row0 + ll) * DIN + h * PP + pp] = f2b(acc[j][q]);
      }
  }
  // states: D[p][n], wave w owns p-strip [16w,16w+16)
  {
    f32x4 acc[8] = {};
#pragma unroll
    for (int kk = 0; kk < 2; ++kk) {
      short8 af = *(const short8*)&xdsT[16 * w + r][kk * 32 + hi * 8];
#pragma unroll
      for (int j = 0; j < 8; ++j) {
        short8 bg = *(const short8*)&BdT[16 * j + r][kk * 32 + hi * 8];
        acc[j] = __builtin_amdgcn_mfma_f32_16x16x32_bf16(af, bg, acc[j], 0, 0, 0);
      }
    }
    size_t sb = ((size_t)(b * NC + c) * HH + h) * (PP * NSD);
#pragma unroll
    for (int j = 0; j < 8; ++j)
#pragma unroll
      for (int q = 0; q < 4; ++q) {
        int pp = 16 * w + hi * 4 + q, nn = 16 * j + r;
        states[sb + (size_t)pp * NSD + nn] = f2b(acc[j][q]);
      }
  }
}

// ---------------------------------------------------------------------------
// Inter-chunk sequential scan, in place (bf16 storage, fp32 carry).
// ---------------------------------------------------------------------------
__global__ __launch_bounds__(256) void scan(bf16* __restrict__ states,
                                            const float* __restrict__ cumA) {
  const int q = blockIdx.x, h = blockIdx.y, b = blockIdx.z;
  const int t = threadIdx.x;
  float S[8] = {};
  for (int c = 0; c < NC; ++c) {
    float tot = expf(cumA[((size_t)(b * HH + h) * NC + c) * CHK + CHK - 1]);
    size_t base = ((size_t)(b * NC + c) * HH + h) * (PP * NSD) + q * 2048 + t;
#pragma unroll
    for (int i = 0; i < 8; ++i) {
      float cs = b2f(states[base + i * 256]);
      states[base + i * 256] = f2b(S[i]);
      S[i] = S[i] * tot + cs;
    }
  }
}

// ---------------------------------------------------------------------------
// Y_off[l][p] = dot(C[l,:], S[p,:]) — MFMA; y += Y_off*exp(cA) + xs*D.
// ---------------------------------------------------------------------------
__global__ __launch_bounds__(256) void yoff(
    const bf16* __restrict__ Cb, const bf16* __restrict__ states,
    const float* __restrict__ cumA, const bf16* __restrict__ xs,
    const float* __restrict__ Dp, bf16* __restrict__ y) {
  const int h = blockIdx.x, c = blockIdx.y, b = blockIdx.z;
  const int row0 = (b * NC + c) * CHK;
  __shared__ short Csh[64][136];
  __shared__ short Ssh[64][136];
  __shared__ float dcy[CHK];
  const int t = threadIdx.x;
  const int lane = t & 63, w = t >> 6;
  if (t < CHK) dcy[t] = expf(cumA[((size_t)(b * HH + h) * NC + c) * CHK + t]);
  const size_t sbase = ((size_t)(b * NC + c) * HH + h) * (PP * NSD);
#pragma unroll
  for (int i = 0; i < 4; ++i) {
    int f = t + i * 256;
    int rr = f >> 4, n0 = (f & 15) * 8;
    *(uint4*)&Csh[rr][n0] = *(const uint4*)&Cb[(size_t)(row0 + rr) * NSD + n0];
    *(uint4*)&Ssh[rr][n0] = *(const uint4*)&states[sbase + (size_t)rr * NSD + n0];
  }
  __syncthreads();
  f32x4 acc[4] = {};
  const int r = lane & 15, hi = lane >> 4;
#pragma unroll
  for (int kk = 0; kk < 4; ++kk) {
    short8 af = *(const short8*)&Csh[16 * w + r][kk * 32 + hi * 8];
#pragma unroll
    for (int j = 0; j < 4; ++j) {
      short8 bg = *(const short8*)&Ssh[16 * j + r][kk * 32 + hi * 8];
      acc[j] = __builtin_amdgcn_mfma_f32_16x16x32_bf16(af, bg, acc[j], 0, 0, 0);
    }
  }
  const float Dh = Dp[h];
#pragma unroll
  for (int j = 0; j < 4; ++j)
#pragma unroll
    for (int q = 0; q < 4; ++q) {
      int ll = 16 * w + hi * 4 + q, pp = 16 * j + r;
      size_t idx = (size_t)(row0 + ll) * DIN + h * PP + pp;
      y[idx] = f2b(b2f(y[idx]) + acc[j][q] * dcy[ll] + b2f(xs[idx]) * Dh);
    }
}

// ---------------------------------------------------------------------------
// yz = y * silu(z); RMS-normalize over d_inner; scale; bf16 out.
// ---------------------------------------------------------------------------
__global__ __launch_bounds__(256) void gatenorm(const bf16* __restrict__ y,
                                                const bf16* __restrict__ zb,
                                                const float* __restrict__ nsc,
                                                bf16* __restrict__ outn) {
  const int row = blockIdx.x, t = threadIdx.x;
  float v[8];
  float ss = 0.f;
#pragma unroll
  for (int i = 0; i < 8; ++i) {
    int ch = t + i * 256;
    float z  = b2f(zb[(size_t)row * DIN + ch]);
    float yv = b2f(y[(size_t)row * DIN + ch]);
    float g  = yv * z / (1.f + expf(-z));
    v[i] = g;
    ss += g * g;
  }
#pragma unroll
  for (int off = 32; off > 0; off >>= 1) ss += __shfl_down(ss, off, 64);
  __shared__ float red[4];
  if ((t & 63) == 0) red[t >> 6] = ss;
  __syncthreads();
  float tot = red[0] + red[1] + red[2] + red[3];
  float r = rsqrtf(tot * (1.f / DIN) + 1e-6f);
#pragma unroll
  for (int i = 0; i < 8; ++i) {
    int ch = t + i * 256;
    outn[(size_t)row * DIN + ch] = f2b(v[i] * r * nsc[ch]);
  }
}

// ---------------------------------------------------------------------------
extern "C" void kernel_launch(void* const* d_in, const int* in_sizes, int n_in,
                              void* d_out, int out_size, void* d_ws, size_t ws_size,
                              hipStream_t stream) {
  const float* x     = (const float*)d_in[0];
  const float* inw   = (const float*)d_in[1];
  const float* convw = (const float*)d_in[2];
  const float* convb = (const float*)d_in[3];
  const float* dtb   = (const float*)d_in[4];
  const float* alog  = (const float*)d_in[5];
  const float* Dp    = (const float*)d_in[6];
  const float* nsc   = (const float*)d_in[7];
  const float* outw  = (const float*)d_in[8];
  float* out = (float*)d_out;

  // workspace layout — ~209 MB total (bf16 intermediates, aliased reuse)
  char* p = (char*)d_ws;
  bf16*  zb     = (bf16*)p;  p += (size_t)ROWS * DIN * 2;          //  33.6 MB
  bf16*  xbcb   = (bf16*)p;  p += (size_t)ROWS * CONVD * 2;        //  37.7 MB
  bf16*  y      = xbcb;      // reuse: conv consumes xbcb before y is written
  float* dtraw  = (float*)p; p += (size_t)ROWS * HH * 4;           //   1.0 MB
  bf16*  xs     = (bf16*)p;  p += (size_t)ROWS * DIN * 2;          //  33.6 MB
  bf16*  states = (bf16*)p;  p += (size_t)BB * NC * HH * PP * NSD * 2; // 67.1 MB
  bf16*  normb  = states;    // reuse: yoff consumes states before norm written
  bf16*  Bb     = (bf16*)p;  p += (size_t)ROWS * NSD * 2;          //   2.1 MB
  bf16*  Cb     = (bf16*)p;  p += (size_t)ROWS * NSD * 2;          //   2.1 MB
  float* dtv    = (float*)p; p += (size_t)ROWS * HH * 4;           //   1.0 MB
  float* dtA    = (float*)p; p += (size_t)ROWS * HH * 4;           //   1.0 MB
  float* cumA   = (float*)p; p += (size_t)BB * HH * NC * CHK * 4;  //   1.0 MB
  float* G      = (float*)p; p += (size_t)BB * NC * CHK * CHK * 4; //   2.1 MB
  bf16*  xb     = (bf16*)p;  p += (size_t)ROWS * DM * 2;           //  16.8 MB
  bf16*  BtIn   = (bf16*)p;  p += (size_t)NPAD * DM * 2;           //   9.2 MB
  bf16*  BtOut  = xb;        // reuse: xb dead after in_proj GEMM

  // 0a. x -> bf16
  convert_bf16<<<(ROWS * DM / 4 + 255) / 256, 256, 0, stream>>>(x, xb, ROWS * DM / 4);
  // 0b. in_proj_w [DM][DPROJ] -> BtIn bf16 [NPAD][DM]
  transpose_w<<<dim3(NPAD / 32, DM / 32), 256, 0, stream>>>(inw, BtIn, DM, DPROJ);
  // 1. in_proj GEMM (MFMA, split outputs)
  gemm_mfma<0><<<dim3(NPAD / 128, ROWS / 128), 256, 0, stream>>>(
      (const short*)xb, (const short*)BtIn, DM, zb, xbcb, dtraw, nullptr);
  // 0c. out_proj_w [DIN][DM] -> BtOut bf16 [DM][DIN]  (into dead xb region)
  transpose_w<<<dim3(DM / 32, DIN / 32), 256, 0, stream>>>(outw, BtOut, DIN, DM);
  // 2. conv + activations + splits (bf16 B/C)
  conv_act<<<ROWS, 256, 0, stream>>>(xbcb, dtraw, convw, convb, dtb, alog,
                                     xs, Bb, Cb, dtv, dtA);
  // 3. G = C B^T per chunk (MFMA)
  gmat<<<dim3(NC, BB), 256, 0, stream>>>(Bb, Cb, G);
  // 4. Y_diag + chunk states per (b,c,h) (MFMA; y overwrites xbcb region)
  ssd_chunk<<<dim3(HH, NC, BB), 256, 0, stream>>>(G, xs, Bb, dtv, dtA,
                                                  y, states, cumA);
  // 5. inter-chunk scan (in place)
  scan<<<dim3(4, HH, BB), 256, 0, stream>>>(states, cumA);
  // 6. Y_off + D-term (MFMA)
  yoff<<<dim3(HH, NC, BB), 256, 0, stream>>>(Cb, states, cumA, xs, Dp, y);
  // 7. gate + RMSNorm (normed overwrites states region)
  gatenorm<<<ROWS, 256, 0, stream>>>(y, zb, nsc, normb);
  // 8. out_proj GEMM (MFMA, fp32 out)
  gemm_mfma<1><<<dim3(DM / 128, ROWS / 128), 256, 0, stream>>>(
      (const short*)normb, (const short*)BtOut, DIN, nullptr, nullptr, nullptr, out);

  (void)in_sizes; (void)n_in; (void)out_size; (void)ws_size;
}

// Round 5
// 383.926 us; speedup vs baseline: 4.7063x; 1.0020x over previous
//
#include <hip/hip_runtime.h>
#include <hip/hip_bf16.h>
#include <math.h>

typedef __hip_bfloat16 bf16;
typedef __attribute__((ext_vector_type(8))) short short8;
typedef __attribute__((ext_vector_type(4))) float f32x4;

constexpr int BB    = 2;      // batch
constexpr int LL    = 4096;   // seq len
constexpr int DM    = 1024;   // d_model
constexpr int DIN   = 2048;   // d_inner
constexpr int HH    = 32;     // n_heads
constexpr int PP    = 64;     // head_dim
constexpr int NSD   = 128;    // d_state
constexpr int CONVD = 2304;   // d_inner + 2*d_state
constexpr int DPROJ = 4384;   // 2*d_inner + 2*d_state + n_heads
constexpr int NPAD  = 4480;   // DPROJ padded to 35*128
constexpr int CHK   = 64;     // chunk size
constexpr int NC    = 64;     // chunks per batch (L/CHK)
constexpr int ROWS  = BB * LL; // 8192

__device__ __forceinline__ float b2f(bf16 v) { return __bfloat162float(v); }
__device__ __forceinline__ bf16  f2b(float f) { return __float2bfloat16(f); }
__device__ __forceinline__ short f2bs(float f) {
  bf16 b = f2b(f);
  return *reinterpret_cast<short*>(&b);
}
// async global->LDS, 16B per lane; LDS dest = base + lane*16 (wave-uniform base)
__device__ __forceinline__ void gload16(const short* g, short* l) {
  __builtin_amdgcn_global_load_lds(
      (const __attribute__((address_space(1))) void*)g,
      (__attribute__((address_space(3))) void*)l, 16, 0, 0);
}

// ---------------------------------------------------------------------------
// fp32 -> bf16 elementwise (x input for in_proj GEMM). 4 elems/thread.
// ---------------------------------------------------------------------------
__global__ __launch_bounds__(256) void convert_bf16(const float* __restrict__ in,
                                                    bf16* __restrict__ outp, int n4) {
  int i = blockIdx.x * 256 + threadIdx.x;
  if (i >= n4) return;
  float4 v = *(const float4*)&in[(size_t)i * 4];
  bf16* p = &outp[(size_t)i * 4];
  p[0] = f2b(v.x); p[1] = f2b(v.y); p[2] = f2b(v.z); p[3] = f2b(v.w);
}

// ---------------------------------------------------------------------------
// Transpose + convert: W fp32 [K][N] row-major -> Bt bf16 [Npad][K] row-major.
// ---------------------------------------------------------------------------
__global__ __launch_bounds__(256) void transpose_w(const float* __restrict__ W,
                                                   bf16* __restrict__ Bt,
                                                   int K, int N) {
  __shared__ float Tl[32][33];
  const int n0 = blockIdx.x * 32, k0 = blockIdx.y * 32;
  const int t = threadIdx.x;
  {
    const int kk = t >> 3, nn4 = (t & 7) * 4;
#pragma unroll
    for (int j = 0; j < 4; ++j) {
      int n = n0 + nn4 + j;
      Tl[kk][nn4 + j] = (n < N) ? W[(size_t)(k0 + kk) * N + n] : 0.f;
    }
  }
  __syncthreads();
  {
    const int nn = t >> 3, kk4 = (t & 7) * 4;
#pragma unroll
    for (int j = 0; j < 4; ++j)
      Bt[(size_t)(n0 + nn) * K + k0 + kk4 + j] = f2b(Tl[kk4 + j][nn]);
  }
}

// ---------------------------------------------------------------------------
// bf16 MFMA GEMM, 128x128 tile, BK=32, 4 waves (2x2), 4x4 16x16x32 tiles/wave.
// Staging via global_load_lds width=16 (m97 pattern): linear LDS [row][32k],
// per-lane global src (row = lane>>2, 16B-slot = lane&3), wave-uniform dest.
// MODE 0: split store zb/xbcb/dtraw (in_proj). MODE 1: fp32 C (out_proj).
// ---------------------------------------------------------------------------
template <int MODE>
__global__ __launch_bounds__(256) void gemm_mfma(
    const short* __restrict__ A, const short* __restrict__ Bt, int K,
    bf16* __restrict__ zb, bf16* __restrict__ xbcb,
    float* __restrict__ dtraw, float* __restrict__ Cout) {
  __shared__ short Asl[128 * 32];
  __shared__ short Bsl[128 * 32];
  const int t = threadIdx.x;
  const int l = t & 63;
  const int w = t >> 6;            // wave id (uniform within wave)
  const int wr = w >> 1, wc = w & 1;
  const int m0 = blockIdx.y * 128;
  const int n0 = blockIdx.x * 128;
  const int srow = l >> 2;         // staging: source row within 16-row block
  const int sk   = (l & 3) * 8;    // staging: k offset (shorts)
  f32x4 acc[4][4] = {};

  for (int k0 = 0; k0 < K; k0 += 32) {
    // stage A,B tiles: per wave 2 blocks of 16 rows each, 1024B per instr
#pragma unroll
    for (int i = 0; i < 2; ++i) {
      int rbase = (i * 4 + w) * 16;
      gload16(&A[(size_t)(m0 + rbase + srow) * K + k0 + sk],
              &Asl[rbase * 32]);
      gload16(&Bt[(size_t)(n0 + rbase + srow) * K + k0 + sk],
              &Bsl[rbase * 32]);
    }
    __syncthreads();
    short8 af[4], bg[4];
#pragma unroll
    for (int i = 0; i < 4; ++i) {
      int ar = wr * 64 + i * 16 + (l & 15);
      af[i] = *(const short8*)&Asl[ar * 32 + (l >> 4) * 8];
      int br = wc * 64 + i * 16 + (l & 15);
      bg[i] = *(const short8*)&Bsl[br * 32 + (l >> 4) * 8];
    }
#pragma unroll
    for (int i = 0; i < 4; ++i)
#pragma unroll
      for (int j = 0; j < 4; ++j)
        acc[i][j] = __builtin_amdgcn_mfma_f32_16x16x32_bf16(af[i], bg[j],
                                                            acc[i][j], 0, 0, 0);
    __syncthreads();
  }
#pragma unroll
  for (int i = 0; i < 4; ++i) {
#pragma unroll
    for (int j = 0; j < 4; ++j) {
      int gcol = n0 + wc * 64 + j * 16 + (l & 15);
      int grow0 = m0 + wr * 64 + i * 16 + (l >> 4) * 4;
#pragma unroll
      for (int q = 0; q < 4; ++q) {
        float v = acc[i][j][q];
        int grow = grow0 + q;
        if constexpr (MODE == 0) {
          if (gcol < DIN) {
            zb[(size_t)grow * DIN + gcol] = f2b(v);
          } else if (gcol < DIN + CONVD) {
            xbcb[(size_t)grow * CONVD + (gcol - DIN)] = f2b(v);
          } else if (gcol < DPROJ) {
            dtraw[(size_t)grow * HH + (gcol - DIN - CONVD)] = v;
          }
        } else {
          Cout[(size_t)grow * DM + gcol] = v;
        }
      }
    }
  }
}

// ---------------------------------------------------------------------------
// Depthwise causal conv1d (k=4) + bias + silu + splits; dt softplus; dtA.
// 8 channels per thread, uint4 (8x bf16) loads/stores.
// ---------------------------------------------------------------------------
__global__ __launch_bounds__(256) void conv_act(
    const bf16* __restrict__ xbc, const float* __restrict__ dtraw,
    const float* __restrict__ convw, const float* __restrict__ convb,
    const float* __restrict__ dtb, const float* __restrict__ alog,
    bf16* __restrict__ xs, bf16* __restrict__ Bb, bf16* __restrict__ Cb,
    float* __restrict__ dtv, float* __restrict__ dtA) {
  const int row = blockIdx.x;
  const int l   = row & (LL - 1);
  const int t   = threadIdx.x;
  if (t < HH) {
    float raw = dtraw[(size_t)row * HH + t] + dtb[t];
    float dt  = (raw > 20.f) ? raw : log1pf(expf(raw));
    dtv[(size_t)row * HH + t] = dt;
    dtA[(size_t)row * HH + t] = -expf(alog[t]) * dt;
  }
  for (int ch = t * 8; ch < CONVD; ch += 2048) {
    float acc[8];
#pragma unroll
    for (int j = 0; j < 8; ++j) acc[j] = convb[ch + j];
#pragma unroll
    for (int k = 0; k < 4; ++k) {
      if (l - 3 + k >= 0) {
        uint4 v = *(const uint4*)&xbc[(size_t)(row - 3 + k) * CONVD + ch];
        const bf16* pv = (const bf16*)&v;
        const float* wp = &convw[k * CONVD + ch];
#pragma unroll
        for (int j = 0; j < 8; ++j) acc[j] += b2f(pv[j]) * wp[j];
      }
    }
    short8 sv;
#pragma unroll
    for (int j = 0; j < 8; ++j) {
      float s = acc[j] / (1.f + expf(-acc[j])); // silu
      sv[j] = f2bs(s);
    }
    if (ch < DIN) {
      *(short8*)&xs[(size_t)row * DIN + ch] = sv;
    } else if (ch < DIN + NSD) {
      *(short8*)&Bb[(size_t)row * NSD + (ch - DIN)] = sv;
    } else {
      *(short8*)&Cb[(size_t)row * NSD + (ch - DIN - NSD)] = sv;
    }
  }
}

// ---------------------------------------------------------------------------
// G[b,c,l,s] = dot(C[l,:], B[s,:]) — MFMA. One block per (b,c).
// ---------------------------------------------------------------------------
__global__ __launch_bounds__(256) void gmat(const bf16* __restrict__ Bb,
                                            const bf16* __restrict__ Cb,
                                            float* __restrict__ G) {
  const int c = blockIdx.x, b = blockIdx.y;
  const int row0 = (b * NC + c) * CHK;
  __shared__ short Csh[64][136];  // pad 8 shorts: row stride 272B (16B-mult)
  __shared__ short Bsh[64][136];
  const int t = threadIdx.x;
  const int lane = t & 63, w = t >> 6;
#pragma unroll
  for (int i = 0; i < 4; ++i) {
    int f = t + i * 256;        // 0..1023
    int rr = f >> 4, n0 = (f & 15) * 8;
    *(uint4*)&Csh[rr][n0] = *(const uint4*)&Cb[(size_t)(row0 + rr) * NSD + n0];
    *(uint4*)&Bsh[rr][n0] = *(const uint4*)&Bb[(size_t)(row0 + rr) * NSD + n0];
  }
  __syncthreads();
  f32x4 acc[4] = {};
  const int r = lane & 15, hi = lane >> 4;
#pragma unroll
  for (int kk = 0; kk < 4; ++kk) {
    short8 af = *(const short8*)&Csh[16 * w + r][kk * 32 + hi * 8];
#pragma unroll
    for (int j = 0; j < 4; ++j) {
      short8 bg = *(const short8*)&Bsh[16 * j + r][kk * 32 + hi * 8];
      acc[j] = __builtin_amdgcn_mfma_f32_16x16x32_bf16(af, bg, acc[j], 0, 0, 0);
    }
  }
#pragma unroll
  for (int j = 0; j < 4; ++j)
#pragma unroll
    for (int q = 0; q < 4; ++q) {
      int ll = 16 * w + hi * 4 + q, ss = 16 * j + r;
      G[((size_t)(b * NC + c) * CHK + ll) * CHK + ss] = acc[j][q];
    }
}

// ---------------------------------------------------------------------------
// Per (b,c,h): cumsum(dtA); Y_diag = GM @ xds (MFMA); states = xds^T·dec @ B.
// ---------------------------------------------------------------------------
__global__ __launch_bounds__(256) void ssd_chunk(
    const float* __restrict__ G, const bf16* __restrict__ xsp,
    const bf16* __restrict__ Bb, const float* __restrict__ dtv,
    const float* __restrict__ dtA,
    bf16* __restrict__ y, bf16* __restrict__ states, float* __restrict__ cumA) {
  const int h = blockIdx.x, c = blockIdx.y, b = blockIdx.z;
  const int row0 = (b * NC + c) * CHK;
  __shared__ short GMb[64][72];   // A for Y_diag: rows l, k=s contig
  __shared__ short xdsT[64][72];  // [p][l]: B for Y_diag (k=s), A for states (k=l)
  __shared__ short BdT[128][72];  // [n][l], dec folded: B for states
  __shared__ float sA[CHK], cA[CHK], dec[CHK], sdt[CHK];
  const int t = threadIdx.x;
  const int lane = t & 63, w = t >> 6;
  if (t < CHK) {
    sA[t]  = dtA[(size_t)(row0 + t) * HH + h];
    sdt[t] = dtv[(size_t)(row0 + t) * HH + h];
  }
  __syncthreads();
  if (t == 0) {
    float s = 0.f;
    for (int i = 0; i < CHK; ++i) { s += sA[i]; cA[i] = s; }
  }
  __syncthreads();
  if (t < CHK) {
    dec[t] = expf(cA[CHK - 1] - cA[t]);
    cumA[((size_t)(b * HH + h) * NC + c) * CHK + t] = cA[t];
  }
  // stage xdsT[p][l] = xs[row0+l][h*64+p] * dt[l]
#pragma unroll
  for (int i = 0; i < 2; ++i) {
    int f = t + i * 256;          // 0..511
    int ll = f >> 3, p0 = (f & 7) * 8;
    uint4 v = *(const uint4*)&xsp[(size_t)(row0 + ll) * DIN + h * PP + p0];
    const bf16* pv = (const bf16*)&v;
    float dtl = sdt[ll];
#pragma unroll
    for (int j = 0; j < 8; ++j) xdsT[p0 + j][ll] = f2bs(b2f(pv[j]) * dtl);
  }
  // stage GM[l][s] = (s<=l) ? G*exp(cA[l]-cA[s]) : 0  (bf16)
#pragma unroll
  for (int i = 0; i < 4; ++i) {
    int f = t + i * 256;          // 0..1023
    int ll = f >> 4, s0 = (f & 15) * 4;
    float4 g = *(const float4*)&G[((size_t)(b * NC + c) * CHK + ll) * CHK + s0];
    float ca = cA[ll];
    GMb[ll][s0 + 0] = f2bs((s0 + 0 <= ll) ? g.x * expf(ca - cA[s0 + 0]) : 0.f);
    GMb[ll][s0 + 1] = f2bs((s0 + 1 <= ll) ? g.y * expf(ca - cA[s0 + 1]) : 0.f);
    GMb[ll][s0 + 2] = f2bs((s0 + 2 <= ll) ? g.z * expf(ca - cA[s0 + 2]) : 0.f);
    GMb[ll][s0 + 3] = f2bs((s0 + 3 <= ll) ? g.w * expf(ca - cA[s0 + 3]) : 0.f);
  }
  __syncthreads();
  // stage BdT[n][l] = B[row0+l][n] * dec[l]
#pragma unroll
  for (int i = 0; i < 4; ++i) {
    int f = t + i * 256;          // 0..1023
    int ll = f >> 4, n0 = (f & 15) * 8;
    uint4 v = *(const uint4*)&Bb[(size_t)(row0 + ll) * NSD + n0];
    const bf16* pv = (const bf16*)&v;
    float dl = dec[ll];
#pragma unroll
    for (int j = 0; j < 8; ++j) BdT[n0 + j][ll] = f2bs(b2f(pv[j]) * dl);
  }
  __syncthreads();
  const int r = lane & 15, hi = lane >> 4;
  // Y_diag: D[l][p], wave w owns l-strip [16w,16w+16)
  {
    f32x4 acc[4] = {};
#pragma unroll
    for (int kk = 0; kk < 2; ++kk) {
      short8 af = *(const short8*)&GMb[16 * w + r][kk * 32 + hi * 8];
#pragma unroll
      for (int j = 0; j < 4; ++j) {
        short8 bg = *(const short8*)&xdsT[16 * j + r][kk * 32 + hi * 8];
        acc[j] = __builtin_amdgcn_mfma_f32_16x16x32_bf16(af, bg, acc[j], 0, 0, 0);
      }
    }
#pragma unroll
    for (int j = 0; j < 4; ++j)
#pragma unroll
      for (int q = 0; q < 4; ++q) {
        int ll = 16 * w + hi * 4 + q, pp = 16 * j + r;
        y[(size_t)(row0 + ll) * DIN + h * PP + pp] = f2b(acc[j][q]);
      }
  }
  // states: D[p][n], wave w owns p-strip [16w,16w+16)
  {
    f32x4 acc[8] = {};
#pragma unroll
    for (int kk = 0; kk < 2; ++kk) {
      short8 af = *(const short8*)&xdsT[16 * w + r][kk * 32 + hi * 8];
#pragma unroll
      for (int j = 0; j < 8; ++j) {
        short8 bg = *(const short8*)&BdT[16 * j + r][kk * 32 + hi * 8];
        acc[j] = __builtin_amdgcn_mfma_f32_16x16x32_bf16(af, bg, acc[j], 0, 0, 0);
      }
    }
    size_t sb = ((size_t)(b * NC + c) * HH + h) * (PP * NSD);
#pragma unroll
    for (int j = 0; j < 8; ++j)
#pragma unroll
      for (int q = 0; q < 4; ++q) {
        int pp = 16 * w + hi * 4 + q, nn = 16 * j + r;
        states[sb + (size_t)pp * NSD + nn] = f2b(acc[j][q]);
      }
  }
}

// ---------------------------------------------------------------------------
// Inter-chunk sequential scan, in place (bf16 storage, fp32 carry).
// ---------------------------------------------------------------------------
__global__ __launch_bounds__(256) void scan(bf16* __restrict__ states,
                                            const float* __restrict__ cumA) {
  const int q = blockIdx.x, h = blockIdx.y, b = blockIdx.z;
  const int t = threadIdx.x;
  float S[8] = {};
  for (int c = 0; c < NC; ++c) {
    float tot = expf(cumA[((size_t)(b * HH + h) * NC + c) * CHK + CHK - 1]);
    size_t base = ((size_t)(b * NC + c) * HH + h) * (PP * NSD) + q * 2048 + t;
#pragma unroll
    for (int i = 0; i < 8; ++i) {
      float cs = b2f(states[base + i * 256]);
      states[base + i * 256] = f2b(S[i]);
      S[i] = S[i] * tot + cs;
    }
  }
}

// ---------------------------------------------------------------------------
// Y_off[l][p] = dot(C[l,:], S[p,:]) — MFMA; y += Y_off*exp(cA) + xs*D.
// ---------------------------------------------------------------------------
__global__ __launch_bounds__(256) void yoff(
    const bf16* __restrict__ Cb, const bf16* __restrict__ states,
    const float* __restrict__ cumA, const bf16* __restrict__ xs,
    const float* __restrict__ Dp, bf16* __restrict__ y) {
  const int h = blockIdx.x, c = blockIdx.y, b = blockIdx.z;
  const int row0 = (b * NC + c) * CHK;
  __shared__ short Csh[64][136];
  __shared__ short Ssh[64][136];
  __shared__ float dcy[CHK];
  const int t = threadIdx.x;
  const int lane = t & 63, w = t >> 6;
  if (t < CHK) dcy[t] = expf(cumA[((size_t)(b * HH + h) * NC + c) * CHK + t]);
  const size_t sbase = ((size_t)(b * NC + c) * HH + h) * (PP * NSD);
#pragma unroll
  for (int i = 0; i < 4; ++i) {
    int f = t + i * 256;
    int rr = f >> 4, n0 = (f & 15) * 8;
    *(uint4*)&Csh[rr][n0] = *(const uint4*)&Cb[(size_t)(row0 + rr) * NSD + n0];
    *(uint4*)&Ssh[rr][n0] = *(const uint4*)&states[sbase + (size_t)rr * NSD + n0];
  }
  __syncthreads();
  f32x4 acc[4] = {};
  const int r = lane & 15, hi = lane >> 4;
#pragma unroll
  for (int kk = 0; kk < 4; ++kk) {
    short8 af = *(const short8*)&Csh[16 * w + r][kk * 32 + hi * 8];
#pragma unroll
    for (int j = 0; j < 4; ++j) {
      short8 bg = *(const short8*)&Ssh[16 * j + r][kk * 32 + hi * 8];
      acc[j] = __builtin_amdgcn_mfma_f32_16x16x32_bf16(af, bg, acc[j], 0, 0, 0);
    }
  }
  const float Dh = Dp[h];
#pragma unroll
  for (int j = 0; j < 4; ++j)
#pragma unroll
    for (int q = 0; q < 4; ++q) {
      int ll = 16 * w + hi * 4 + q, pp = 16 * j + r;
      size_t idx = (size_t)(row0 + ll) * DIN + h * PP + pp;
      y[idx] = f2b(b2f(y[idx]) + acc[j][q] * dcy[ll] + b2f(xs[idx]) * Dh);
    }
}

// ---------------------------------------------------------------------------
// yz = y * silu(z); RMS-normalize over d_inner; scale; bf16 out.
// ---------------------------------------------------------------------------
__global__ __launch_bounds__(256) void gatenorm(const bf16* __restrict__ y,
                                                const bf16* __restrict__ zb,
                                                const float* __restrict__ nsc,
                                                bf16* __restrict__ outn) {
  const int row = blockIdx.x, t = threadIdx.x;
  float v[8];
  float ss = 0.f;
#pragma unroll
  for (int i = 0; i < 8; ++i) {
    int ch = t + i * 256;
    float z  = b2f(zb[(size_t)row * DIN + ch]);
    float yv = b2f(y[(size_t)row * DIN + ch]);
    float g  = yv * z / (1.f + expf(-z));
    v[i] = g;
    ss += g * g;
  }
#pragma unroll
  for (int off = 32; off > 0; off >>= 1) ss += __shfl_down(ss, off, 64);
  __shared__ float red[4];
  if ((t & 63) == 0) red[t >> 6] = ss;
  __syncthreads();
  float tot = red[0] + red[1] + red[2] + red[3];
  float r = rsqrtf(tot * (1.f / DIN) + 1e-6f);
#pragma unroll
  for (int i = 0; i < 8; ++i) {
    int ch = t + i * 256;
    outn[(size_t)row * DIN + ch] = f2b(v[i] * r * nsc[ch]);
  }
}

// ---------------------------------------------------------------------------
extern "C" void kernel_launch(void* const* d_in, const int* in_sizes, int n_in,
                              void* d_out, int out_size, void* d_ws, size_t ws_size,
                              hipStream_t stream) {
  const float* x     = (const float*)d_in[0];
  const float* inw   = (const float*)d_in[1];
  const float* convw = (const float*)d_in[2];
  const float* convb = (const float*)d_in[3];
  const float* dtb   = (const float*)d_in[4];
  const float* alog  = (const float*)d_in[5];
  const float* Dp    = (const float*)d_in[6];
  const float* nsc   = (const float*)d_in[7];
  const float* outw  = (const float*)d_in[8];
  float* out = (float*)d_out;

  // workspace layout — ~209 MB total (bf16 intermediates, aliased reuse)
  char* p = (char*)d_ws;
  bf16*  zb     = (bf16*)p;  p += (size_t)ROWS * DIN * 2;          //  33.6 MB
  bf16*  xbcb   = (bf16*)p;  p += (size_t)ROWS * CONVD * 2;        //  37.7 MB
  bf16*  y      = xbcb;      // reuse: conv consumes xbcb before y is written
  float* dtraw  = (float*)p; p += (size_t)ROWS * HH * 4;           //   1.0 MB
  bf16*  xs     = (bf16*)p;  p += (size_t)ROWS * DIN * 2;          //  33.6 MB
  bf16*  states = (bf16*)p;  p += (size_t)BB * NC * HH * PP * NSD * 2; // 67.1 MB
  bf16*  normb  = states;    // reuse: yoff consumes states before norm written
  bf16*  Bb     = (bf16*)p;  p += (size_t)ROWS * NSD * 2;          //   2.1 MB
  bf16*  Cb     = (bf16*)p;  p += (size_t)ROWS * NSD * 2;          //   2.1 MB
  float* dtv    = (float*)p; p += (size_t)ROWS * HH * 4;           //   1.0 MB
  float* dtA    = (float*)p; p += (size_t)ROWS * HH * 4;           //   1.0 MB
  float* cumA   = (float*)p; p += (size_t)BB * HH * NC * CHK * 4;  //   1.0 MB
  float* G      = (float*)p; p += (size_t)BB * NC * CHK * CHK * 4; //   2.1 MB
  bf16*  xb     = (bf16*)p;  p += (size_t)ROWS * DM * 2;           //  16.8 MB
  bf16*  BtIn   = (bf16*)p;  p += (size_t)NPAD * DM * 2;           //   9.2 MB
  bf16*  BtOut  = xb;        // reuse: xb dead after in_proj GEMM

  // 0a. x -> bf16
  convert_bf16<<<(ROWS * DM / 4 + 255) / 256, 256, 0, stream>>>(x, xb, ROWS * DM / 4);
  // 0b. in_proj_w [DM][DPROJ] -> BtIn bf16 [NPAD][DM]
  transpose_w<<<dim3(NPAD / 32, DM / 32), 256, 0, stream>>>(inw, BtIn, DM, DPROJ);
  // 1. in_proj GEMM (MFMA, split outputs)
  gemm_mfma<0><<<dim3(NPAD / 128, ROWS / 128), 256, 0, stream>>>(
      (const short*)xb, (const short*)BtIn, DM, zb, xbcb, dtraw, nullptr);
  // 0c. out_proj_w [DIN][DM] -> BtOut bf16 [DM][DIN]  (into dead xb region)
  transpose_w<<<dim3(DM / 32, DIN / 32), 256, 0, stream>>>(outw, BtOut, DIN, DM);
  // 2. conv + activations + splits (bf16 B/C)
  conv_act<<<ROWS, 256, 0, stream>>>(xbcb, dtraw, convw, convb, dtb, alog,
                                     xs, Bb, Cb, dtv, dtA);
  // 3. G = C B^T per chunk (MFMA)
  gmat<<<dim3(NC, BB), 256, 0, stream>>>(Bb, Cb, G);
  // 4. Y_diag + chunk states per (b,c,h) (MFMA; y overwrites xbcb region)
  ssd_chunk<<<dim3(HH, NC, BB), 256, 0, stream>>>(G, xs, Bb, dtv, dtA,
                                                  y, states, cumA);
  // 5. inter-chunk scan (in place)
  scan<<<dim3(4, HH, BB), 256, 0, stream>>>(states, cumA);
  // 6. Y_off + D-term (MFMA)
  yoff<<<dim3(HH, NC, BB), 256, 0, stream>>>(Cb, states, cumA, xs, Dp, y);
  // 7. gate + RMSNorm (normed overwrites states region)
  gatenorm<<<ROWS, 256, 0, stream>>>(y, zb, nsc, normb);
  // 8. out_proj GEMM (MFMA, fp32 out)
  gemm_mfma<1><<<dim3(DM / 128, ROWS / 128), 256, 0, stream>>>(
      (const short*)normb, (const short*)BtOut, DIN, nullptr, nullptr, nullptr, out);

  (void)in_sizes; (void)n_in; (void)out_size; (void)ws_size;
}

// Round 6
// 354.684 us; speedup vs baseline: 5.0943x; 1.0824x over previous
//
#include <hip/hip_runtime.h>
#include <hip/hip_bf16.h>
#include <math.h>

typedef __hip_bfloat16 bf16;
typedef __attribute__((ext_vector_type(8))) short short8;
typedef __attribute__((ext_vector_type(4))) float f32x4;

constexpr int BB    = 2;      // batch
constexpr int LL    = 4096;   // seq len
constexpr int DM    = 1024;   // d_model
constexpr int DIN   = 2048;   // d_inner
constexpr int HH    = 32;     // n_heads
constexpr int PP    = 64;     // head_dim
constexpr int NSD   = 128;    // d_state
constexpr int CONVD = 2304;   // d_inner + 2*d_state
constexpr int DPROJ = 4384;   // 2*d_inner + 2*d_state + n_heads
constexpr int NPAD  = 4480;   // DPROJ padded to 35*128
constexpr int CHK   = 64;     // chunk size
constexpr int NC    = 64;     // chunks per batch (L/CHK)
constexpr int ROWS  = BB * LL; // 8192

__device__ __forceinline__ float b2f(bf16 v) { return __bfloat162float(v); }
__device__ __forceinline__ bf16  f2b(float f) { return __float2bfloat16(f); }
__device__ __forceinline__ short f2bs(float f) {
  bf16 b = f2b(f);
  return *reinterpret_cast<short*>(&b);
}
// async global->LDS, 16B per lane; LDS dest = base + lane*16 (wave-uniform base)
__device__ __forceinline__ void gload16(const short* g, short* l) {
  __builtin_amdgcn_global_load_lds(
      (const __attribute__((address_space(1))) void*)g,
      (__attribute__((address_space(3))) void*)l, 16, 0, 0);
}

// ---------------------------------------------------------------------------
// fp32 -> bf16 elementwise (x input for in_proj GEMM). 4 elems/thread.
// ---------------------------------------------------------------------------
__global__ __launch_bounds__(256) void convert_bf16(const float* __restrict__ in,
                                                    bf16* __restrict__ outp, int n4) {
  int i = blockIdx.x * 256 + threadIdx.x;
  if (i >= n4) return;
  float4 v = *(const float4*)&in[(size_t)i * 4];
  bf16* p = &outp[(size_t)i * 4];
  p[0] = f2b(v.x); p[1] = f2b(v.y); p[2] = f2b(v.z); p[3] = f2b(v.w);
}

// ---------------------------------------------------------------------------
// Transpose + convert: W fp32 [K][N] row-major -> Bt bf16 [Npad][K] row-major.
// ---------------------------------------------------------------------------
__global__ __launch_bounds__(256) void transpose_w(const float* __restrict__ W,
                                                   bf16* __restrict__ Bt,
                                                   int K, int N) {
  __shared__ float Tl[32][33];
  const int n0 = blockIdx.x * 32, k0 = blockIdx.y * 32;
  const int t = threadIdx.x;
  {
    const int kk = t >> 3, nn4 = (t & 7) * 4;
#pragma unroll
    for (int j = 0; j < 4; ++j) {
      int n = n0 + nn4 + j;
      Tl[kk][nn4 + j] = (n < N) ? W[(size_t)(k0 + kk) * N + n] : 0.f;
    }
  }
  __syncthreads();
  {
    const int nn = t >> 3, kk4 = (t & 7) * 4;
#pragma unroll
    for (int j = 0; j < 4; ++j)
      Bt[(size_t)(n0 + nn) * K + k0 + kk4 + j] = f2b(Tl[kk4 + j][nn]);
  }
}

// ---------------------------------------------------------------------------
// bf16 MFMA GEMM, 128x128 tile, BK=32, 4 waves (2x2), 4x4 16x16x32 tiles/wave.
// Staging: global_load_lds width=16, PRE-SWIZZLED global source (rule #21:
// linear LDS dest + inverse-swz source + swz read), double-buffered LDS,
// early STAGE issue, ONE barrier per K-step. Hoisted per-lane pointers.
// MODE 0: split store zb/xbcb/dtraw (in_proj). MODE 1: fp32 C (out_proj).
// ---------------------------------------------------------------------------
template <int MODE>
__global__ __launch_bounds__(256) void gemm_mfma(
    const short* __restrict__ A, const short* __restrict__ Bt, int K,
    bf16* __restrict__ zb, bf16* __restrict__ xbcb,
    float* __restrict__ dtraw, float* __restrict__ Cout) {
  __shared__ short Asl[2][128 * 32];
  __shared__ short Bsl[2][128 * 32];
  const int t = threadIdx.x;
  const int l = t & 63;
  const int w = t >> 6;            // wave id (uniform within wave)
  const int wr = w >> 1, wc = w & 1;
  const int m0 = blockIdx.y * 128;
  const int n0 = blockIdx.x * 128;

  // staging: lane covers tile row rbase + (l>>2), physical 16B slot (l&3).
  // inverse swizzle: phys slot p holds logical slot s, p=(s+((row>>1)&3))&3
  //  -> source slot s = ((l&3) - ((l>>3)&3)) & 3
  const int srow = l >> 2;
  const int sk   = (((l & 3) - ((l >> 3) & 3)) & 3) * 8;  // shorts
  const short* gA0 = &A [(size_t)(m0 + (w    ) * 16 + srow) * K + sk];
  const short* gA1 = &A [(size_t)(m0 + (4 + w) * 16 + srow) * K + sk];
  const short* gB0 = &Bt[(size_t)(n0 + (w    ) * 16 + srow) * K + sk];
  const short* gB1 = &Bt[(size_t)(n0 + (4 + w) * 16 + srow) * K + sk];
  const int ldsA0 = (w * 16) * 32, ldsA1 = ((4 + w) * 16) * 32;

  // fragment read offsets (constant per lane): row ar = wbase + i*16 + fr,
  // swizzled slot s2 = ((l>>4) + ((fr>>1)&3)) & 3  (i-independent)
  const int fr = l & 15;
  const int s2 = (((l >> 4) + ((fr >> 1) & 3)) & 3) * 8;
  const int aoff = (wr * 64 + fr) * 32 + s2;
  const int boff = (wc * 64 + fr) * 32 + s2;

  f32x4 acc[4][4] = {};
  const int nt = K >> 5;

  // prologue: stage tile 0 into buf 0
  gload16(gA0, &Asl[0][ldsA0]); gload16(gA1, &Asl[0][ldsA1]);
  gload16(gB0, &Bsl[0][ldsA0]); gload16(gB1, &Bsl[0][ldsA1]);
  gA0 += 32; gA1 += 32; gB0 += 32; gB1 += 32;
  __syncthreads();

  for (int ti = 0; ti < nt; ++ti) {
    const int cur = ti & 1;
    if (ti + 1 < nt) {  // issue prefetch of next tile into other buffer
      const int nxt = cur ^ 1;
      gload16(gA0, &Asl[nxt][ldsA0]); gload16(gA1, &Asl[nxt][ldsA1]);
      gload16(gB0, &Bsl[nxt][ldsA0]); gload16(gB1, &Bsl[nxt][ldsA1]);
      gA0 += 32; gA1 += 32; gB0 += 32; gB1 += 32;
    }
    short8 af[4], bg[4];
#pragma unroll
    for (int i = 0; i < 4; ++i) {
      af[i] = *(const short8*)&Asl[cur][aoff + i * 512];
      bg[i] = *(const short8*)&Bsl[cur][boff + i * 512];
    }
#pragma unroll
    for (int i = 0; i < 4; ++i)
#pragma unroll
      for (int j = 0; j < 4; ++j)
        acc[i][j] = __builtin_amdgcn_mfma_f32_16x16x32_bf16(af[i], bg[j],
                                                            acc[i][j], 0, 0, 0);
    __syncthreads();  // drains vmcnt (prefetch landed) + protects buf reuse
  }
  // epilogue: D col = lane&15, row = (lane>>4)*4 + q
#pragma unroll
  for (int i = 0; i < 4; ++i) {
#pragma unroll
    for (int j = 0; j < 4; ++j) {
      int gcol = n0 + wc * 64 + j * 16 + (l & 15);
      int grow0 = m0 + wr * 64 + i * 16 + (l >> 4) * 4;
#pragma unroll
      for (int q = 0; q < 4; ++q) {
        float v = acc[i][j][q];
        int grow = grow0 + q;
        if constexpr (MODE == 0) {
          if (gcol < DIN) {
            zb[(size_t)grow * DIN + gcol] = f2b(v);
          } else if (gcol < DIN + CONVD) {
            xbcb[(size_t)grow * CONVD + (gcol - DIN)] = f2b(v);
          } else if (gcol < DPROJ) {
            dtraw[(size_t)grow * HH + (gcol - DIN - CONVD)] = v;
          }
        } else {
          Cout[(size_t)grow * DM + gcol] = v;
        }
      }
    }
  }
}

// ---------------------------------------------------------------------------
// Depthwise causal conv1d (k=4) + bias + silu + splits; dt softplus; dtA.
// ---------------------------------------------------------------------------
__global__ __launch_bounds__(256) void conv_act(
    const bf16* __restrict__ xbc, const float* __restrict__ dtraw,
    const float* __restrict__ convw, const float* __restrict__ convb,
    const float* __restrict__ dtb, const float* __restrict__ alog,
    bf16* __restrict__ xs, bf16* __restrict__ Bb, bf16* __restrict__ Cb,
    float* __restrict__ dtv, float* __restrict__ dtA) {
  const int row = blockIdx.x;
  const int l   = row & (LL - 1);
  const int t   = threadIdx.x;
  if (t < HH) {
    float raw = dtraw[(size_t)row * HH + t] + dtb[t];
    float dt  = (raw > 20.f) ? raw : log1pf(expf(raw));
    dtv[(size_t)row * HH + t] = dt;
    dtA[(size_t)row * HH + t] = -expf(alog[t]) * dt;
  }
  for (int ch = t * 8; ch < CONVD; ch += 2048) {
    float acc[8];
#pragma unroll
    for (int j = 0; j < 8; ++j) acc[j] = convb[ch + j];
#pragma unroll
    for (int k = 0; k < 4; ++k) {
      if (l - 3 + k >= 0) {
        uint4 v = *(const uint4*)&xbc[(size_t)(row - 3 + k) * CONVD + ch];
        const bf16* pv = (const bf16*)&v;
        const float* wp = &convw[k * CONVD + ch];
#pragma unroll
        for (int j = 0; j < 8; ++j) acc[j] += b2f(pv[j]) * wp[j];
      }
    }
    short8 sv;
#pragma unroll
    for (int j = 0; j < 8; ++j) {
      float s = acc[j] / (1.f + expf(-acc[j])); // silu
      sv[j] = f2bs(s);
    }
    if (ch < DIN) {
      *(short8*)&xs[(size_t)row * DIN + ch] = sv;
    } else if (ch < DIN + NSD) {
      *(short8*)&Bb[(size_t)row * NSD + (ch - DIN)] = sv;
    } else {
      *(short8*)&Cb[(size_t)row * NSD + (ch - DIN - NSD)] = sv;
    }
  }
}

// ---------------------------------------------------------------------------
// G[b,c,l,s] = dot(C[l,:], B[s,:]) — MFMA. One block per (b,c).
// ---------------------------------------------------------------------------
__global__ __launch_bounds__(256) void gmat(const bf16* __restrict__ Bb,
                                            const bf16* __restrict__ Cb,
                                            float* __restrict__ G) {
  const int c = blockIdx.x, b = blockIdx.y;
  const int row0 = (b * NC + c) * CHK;
  __shared__ short Csh[64][136];  // pad 8 shorts: row stride 272B (16B-mult)
  __shared__ short Bsh[64][136];
  const int t = threadIdx.x;
  const int lane = t & 63, w = t >> 6;
#pragma unroll
  for (int i = 0; i < 4; ++i) {
    int f = t + i * 256;        // 0..1023
    int rr = f >> 4, n0 = (f & 15) * 8;
    *(uint4*)&Csh[rr][n0] = *(const uint4*)&Cb[(size_t)(row0 + rr) * NSD + n0];
    *(uint4*)&Bsh[rr][n0] = *(const uint4*)&Bb[(size_t)(row0 + rr) * NSD + n0];
  }
  __syncthreads();
  f32x4 acc[4] = {};
  const int r = lane & 15, hi = lane >> 4;
#pragma unroll
  for (int kk = 0; kk < 4; ++kk) {
    short8 af = *(const short8*)&Csh[16 * w + r][kk * 32 + hi * 8];
#pragma unroll
    for (int j = 0; j < 4; ++j) {
      short8 bg = *(const short8*)&Bsh[16 * j + r][kk * 32 + hi * 8];
      acc[j] = __builtin_amdgcn_mfma_f32_16x16x32_bf16(af, bg, acc[j], 0, 0, 0);
    }
  }
#pragma unroll
  for (int j = 0; j < 4; ++j)
#pragma unroll
    for (int q = 0; q < 4; ++q) {
      int ll = 16 * w + hi * 4 + q, ss = 16 * j + r;
      G[((size_t)(b * NC + c) * CHK + ll) * CHK + ss] = acc[j][q];
    }
}

// ---------------------------------------------------------------------------
// Per (b,c,h): cumsum(dtA); Y_diag = GM @ xds (MFMA); states = xds^T·dec @ B.
// ---------------------------------------------------------------------------
__global__ __launch_bounds__(256) void ssd_chunk(
    const float* __restrict__ G, const bf16* __restrict__ xsp,
    const bf16* __restrict__ Bb, const float* __restrict__ dtv,
    const float* __restrict__ dtA,
    bf16* __restrict__ y, bf16* __restrict__ states, float* __restrict__ cumA) {
  const int h = blockIdx.x, c = blockIdx.y, b = blockIdx.z;
  const int row0 = (b * NC + c) * CHK;
  __shared__ short GMb[64][72];   // A for Y_diag: rows l, k=s contig
  __shared__ short xdsT[64][72];  // [p][l]: B for Y_diag (k=s), A for states (k=l)
  __shared__ short BdT[128][72];  // [n][l], dec folded: B for states
  __shared__ float sA[CHK], cA[CHK], dec[CHK], sdt[CHK];
  const int t = threadIdx.x;
  const int lane = t & 63, w = t >> 6;
  if (t < CHK) {
    sA[t]  = dtA[(size_t)(row0 + t) * HH + h];
    sdt[t] = dtv[(size_t)(row0 + t) * HH + h];
  }
  __syncthreads();
  if (t == 0) {
    float s = 0.f;
    for (int i = 0; i < CHK; ++i) { s += sA[i]; cA[i] = s; }
  }
  __syncthreads();
  if (t < CHK) {
    dec[t] = expf(cA[CHK - 1] - cA[t]);
    cumA[((size_t)(b * HH + h) * NC + c) * CHK + t] = cA[t];
  }
  // stage xdsT[p][l] = xs[row0+l][h*64+p] * dt[l]
#pragma unroll
  for (int i = 0; i < 2; ++i) {
    int f = t + i * 256;          // 0..511
    int ll = f >> 3, p0 = (f & 7) * 8;
    uint4 v = *(const uint4*)&xsp[(size_t)(row0 + ll) * DIN + h * PP + p0];
    const bf16* pv = (const bf16*)&v;
    float dtl = sdt[ll];
#pragma unroll
    for (int j = 0; j < 8; ++j) xdsT[p0 + j][ll] = f2bs(b2f(pv[j]) * dtl);
  }
  // stage GM[l][s] = (s<=l) ? G*exp(cA[l]-cA[s]) : 0  (bf16)
#pragma unroll
  for (int i = 0; i < 4; ++i) {
    int f = t + i * 256;          // 0..1023
    int ll = f >> 4, s0 = (f & 15) * 4;
    float4 g = *(const float4*)&G[((size_t)(b * NC + c) * CHK + ll) * CHK + s0];
    float ca = cA[ll];
    GMb[ll][s0 + 0] = f2bs((s0 + 0 <= ll) ? g.x * expf(ca - cA[s0 + 0]) : 0.f);
    GMb[ll][s0 + 1] = f2bs((s0 + 1 <= ll) ? g.y * expf(ca - cA[s0 + 1]) : 0.f);
    GMb[ll][s0 + 2] = f2bs((s0 + 2 <= ll) ? g.z * expf(ca - cA[s0 + 2]) : 0.f);
    GMb[ll][s0 + 3] = f2bs((s0 + 3 <= ll) ? g.w * expf(ca - cA[s0 + 3]) : 0.f);
  }
  __syncthreads();
  // stage BdT[n][l] = B[row0+l][n] * dec[l]
#pragma unroll
  for (int i = 0; i < 4; ++i) {
    int f = t + i * 256;          // 0..1023
    int ll = f >> 4, n0 = (f & 15) * 8;
    uint4 v = *(const uint4*)&Bb[(size_t)(row0 + ll) * NSD + n0];
    const bf16* pv = (const bf16*)&v;
    float dl = dec[ll];
#pragma unroll
    for (int j = 0; j < 8; ++j) BdT[n0 + j][ll] = f2bs(b2f(pv[j]) * dl);
  }
  __syncthreads();
  const int r = lane & 15, hi = lane >> 4;
  // Y_diag: D[l][p], wave w owns l-strip [16w,16w+16)
  {
    f32x4 acc[4] = {};
#pragma unroll
    for (int kk = 0; kk < 2; ++kk) {
      short8 af = *(const short8*)&GMb[16 * w + r][kk * 32 + hi * 8];
#pragma unroll
      for (int j = 0; j < 4; ++j) {
        short8 bg = *(const short8*)&xdsT[16 * j + r][kk * 32 + hi * 8];
        acc[j] = __builtin_amdgcn_mfma_f32_16x16x32_bf16(af, bg, acc[j], 0, 0, 0);
      }
    }
#pragma unroll
    for (int j = 0; j < 4; ++j)
#pragma unroll
      for (int q = 0; q < 4; ++q) {
        int ll = 16 * w + hi * 4 + q, pp = 16 * j + r;
        y[(size_t)(row0 + ll) * DIN + h * PP + pp] = f2b(acc[j][q]);
      }
  }
  // states: D[p][n], wave w owns p-strip [16w,16w+16)
  {
    f32x4 acc[8] = {};
#pragma unroll
    for (int kk = 0; kk < 2; ++kk) {
      short8 af = *(const short8*)&xdsT[16 * w + r][kk * 32 + hi * 8];
#pragma unroll
      for (int j = 0; j < 8; ++j) {
        short8 bg = *(const short8*)&BdT[16 * j + r][kk * 32 + hi * 8];
        acc[j] = __builtin_amdgcn_mfma_f32_16x16x32_bf16(af, bg, acc[j], 0, 0, 0);
      }
    }
    size_t sb = ((size_t)(b * NC + c) * HH + h) * (PP * NSD);
#pragma unroll
    for (int j = 0; j < 8; ++j)
#pragma unroll
      for (int q = 0; q < 4; ++q) {
        int pp = 16 * w + hi * 4 + q, nn = 16 * j + r;
        states[sb + (size_t)pp * NSD + nn] = f2b(acc[j][q]);
      }
  }
}

// ---------------------------------------------------------------------------
// Inter-chunk sequential scan, in place (bf16 storage, fp32 carry).
// ---------------------------------------------------------------------------
__global__ __launch_bounds__(256) void scan(bf16* __restrict__ states,
                                            const float* __restrict__ cumA) {
  const int q = blockIdx.x, h = blockIdx.y, b = blockIdx.z;
  const int t = threadIdx.x;
  float S[8] = {};
  for (int c = 0; c < NC; ++c) {
    float tot = expf(cumA[((size_t)(b * HH + h) * NC + c) * CHK + CHK - 1]);
    size_t base = ((size_t)(b * NC + c) * HH + h) * (PP * NSD) + q * 2048 + t;
#pragma unroll
    for (int i = 0; i < 8; ++i) {
      float cs = b2f(states[base + i * 256]);
      states[base + i * 256] = f2b(S[i]);
      S[i] = S[i] * tot + cs;
    }
  }
}

// ---------------------------------------------------------------------------
// Y_off[l][p] = dot(C[l,:], S[p,:]) — MFMA; y += Y_off*exp(cA) + xs*D.
// ---------------------------------------------------------------------------
__global__ __launch_bounds__(256) void yoff(
    const bf16* __restrict__ Cb, const bf16* __restrict__ states,
    const float* __restrict__ cumA, const bf16* __restrict__ xs,
    const float* __restrict__ Dp, bf16* __restrict__ y) {
  const int h = blockIdx.x, c = blockIdx.y, b = blockIdx.z;
  const int row0 = (b * NC + c) * CHK;
  __shared__ short Csh[64][136];
  __shared__ short Ssh[64][136];
  __shared__ float dcy[CHK];
  const int t = threadIdx.x;
  const int lane = t & 63, w = t >> 6;
  if (t < CHK) dcy[t] = expf(cumA[((size_t)(b * HH + h) * NC + c) * CHK + t]);
  const size_t sbase = ((size_t)(b * NC + c) * HH + h) * (PP * NSD);
#pragma unroll
  for (int i = 0; i < 4; ++i) {
    int f = t + i * 256;
    int rr = f >> 4, n0 = (f & 15) * 8;
    *(uint4*)&Csh[rr][n0] = *(const uint4*)&Cb[(size_t)(row0 + rr) * NSD + n0];
    *(uint4*)&Ssh[rr][n0] = *(const uint4*)&states[sbase + (size_t)rr * NSD + n0];
  }
  __syncthreads();
  f32x4 acc[4] = {};
  const int r = lane & 15, hi = lane >> 4;
#pragma unroll
  for (int kk = 0; kk < 4; ++kk) {
    short8 af = *(const short8*)&Csh[16 * w + r][kk * 32 + hi * 8];
#pragma unroll
    for (int j = 0; j < 4; ++j) {
      short8 bg = *(const short8*)&Ssh[16 * j + r][kk * 32 + hi * 8];
      acc[j] = __builtin_amdgcn_mfma_f32_16x16x32_bf16(af, bg, acc[j], 0, 0, 0);
    }
  }
  const float Dh = Dp[h];
#pragma unroll
  for (int j = 0; j < 4; ++j)
#pragma unroll
    for (int q = 0; q < 4; ++q) {
      int ll = 16 * w + hi * 4 + q, pp = 16 * j + r;
      size_t idx = (size_t)(row0 + ll) * DIN + h * PP + pp;
      y[idx] = f2b(b2f(y[idx]) + acc[j][q] * dcy[ll] + b2f(xs[idx]) * Dh);
    }
}

// ---------------------------------------------------------------------------
// yz = y * silu(z); RMS-normalize over d_inner; scale; bf16 out.
// ---------------------------------------------------------------------------
__global__ __launch_bounds__(256) void gatenorm(const bf16* __restrict__ y,
                                                const bf16* __restrict__ zb,
                                                const float* __restrict__ nsc,
                                                bf16* __restrict__ outn) {
  const int row = blockIdx.x, t = threadIdx.x;
  float v[8];
  float ss = 0.f;
#pragma unroll
  for (int i = 0; i < 8; ++i) {
    int ch = t + i * 256;
    float z  = b2f(zb[(size_t)row * DIN + ch]);
    float yv = b2f(y[(size_t)row * DIN + ch]);
    float g  = yv * z / (1.f + expf(-z));
    v[i] = g;
    ss += g * g;
  }
#pragma unroll
  for (int off = 32; off > 0; off >>= 1) ss += __shfl_down(ss, off, 64);
  __shared__ float red[4];
  if ((t & 63) == 0) red[t >> 6] = ss;
  __syncthreads();
  float tot = red[0] + red[1] + red[2] + red[3];
  float r = rsqrtf(tot * (1.f / DIN) + 1e-6f);
#pragma unroll
  for (int i = 0; i < 8; ++i) {
    int ch = t + i * 256;
    outn[(size_t)row * DIN + ch] = f2b(v[i] * r * nsc[ch]);
  }
}

// ---------------------------------------------------------------------------
extern "C" void kernel_launch(void* const* d_in, const int* in_sizes, int n_in,
                              void* d_out, int out_size, void* d_ws, size_t ws_size,
                              hipStream_t stream) {
  const float* x     = (const float*)d_in[0];
  const float* inw   = (const float*)d_in[1];
  const float* convw = (const float*)d_in[2];
  const float* convb = (const float*)d_in[3];
  const float* dtb   = (const float*)d_in[4];
  const float* alog  = (const float*)d_in[5];
  const float* Dp    = (const float*)d_in[6];
  const float* nsc   = (const float*)d_in[7];
  const float* outw  = (const float*)d_in[8];
  float* out = (float*)d_out;

  // workspace layout — ~209 MB total (bf16 intermediates, aliased reuse)
  char* p = (char*)d_ws;
  bf16*  zb     = (bf16*)p;  p += (size_t)ROWS * DIN * 2;          //  33.6 MB
  bf16*  xbcb   = (bf16*)p;  p += (size_t)ROWS * CONVD * 2;        //  37.7 MB
  bf16*  y      = xbcb;      // reuse: conv consumes xbcb before y is written
  float* dtraw  = (float*)p; p += (size_t)ROWS * HH * 4;           //   1.0 MB
  bf16*  xs     = (bf16*)p;  p += (size_t)ROWS * DIN * 2;          //  33.6 MB
  bf16*  states = (bf16*)p;  p += (size_t)BB * NC * HH * PP * NSD * 2; // 67.1 MB
  bf16*  normb  = states;    // reuse: yoff consumes states before norm written
  bf16*  Bb     = (bf16*)p;  p += (size_t)ROWS * NSD * 2;          //   2.1 MB
  bf16*  Cb     = (bf16*)p;  p += (size_t)ROWS * NSD * 2;          //   2.1 MB
  float* dtv    = (float*)p; p += (size_t)ROWS * HH * 4;           //   1.0 MB
  float* dtA    = (float*)p; p += (size_t)ROWS * HH * 4;           //   1.0 MB
  float* cumA   = (float*)p; p += (size_t)BB * HH * NC * CHK * 4;  //   1.0 MB
  float* G      = (float*)p; p += (size_t)BB * NC * CHK * CHK * 4; //   2.1 MB
  bf16*  xb     = (bf16*)p;  p += (size_t)ROWS * DM * 2;           //  16.8 MB
  bf16*  BtIn   = (bf16*)p;  p += (size_t)NPAD * DM * 2;           //   9.2 MB
  bf16*  BtOut  = xb;        // reuse: xb dead after in_proj GEMM

  // 0a. x -> bf16
  convert_bf16<<<(ROWS * DM / 4 + 255) / 256, 256, 0, stream>>>(x, xb, ROWS * DM / 4);
  // 0b. in_proj_w [DM][DPROJ] -> BtIn bf16 [NPAD][DM]
  transpose_w<<<dim3(NPAD / 32, DM / 32), 256, 0, stream>>>(inw, BtIn, DM, DPROJ);
  // 1. in_proj GEMM (MFMA, split outputs)
  gemm_mfma<0><<<dim3(NPAD / 128, ROWS / 128), 256, 0, stream>>>(
      (const short*)xb, (const short*)BtIn, DM, zb, xbcb, dtraw, nullptr);
  // 0c. out_proj_w [DIN][DM] -> BtOut bf16 [DM][DIN]  (into dead xb region)
  transpose_w<<<dim3(DM / 32, DIN / 32), 256, 0, stream>>>(outw, BtOut, DIN, DM);
  // 2. conv + activations + splits (bf16 B/C)
  conv_act<<<ROWS, 256, 0, stream>>>(xbcb, dtraw, convw, convb, dtb, alog,
                                     xs, Bb, Cb, dtv, dtA);
  // 3. G = C B^T per chunk (MFMA)
  gmat<<<dim3(NC, BB), 256, 0, stream>>>(Bb, Cb, G);
  // 4. Y_diag + chunk states per (b,c,h) (MFMA; y overwrites xbcb region)
  ssd_chunk<<<dim3(HH, NC, BB), 256, 0, stream>>>(G, xs, Bb, dtv, dtA,
                                                  y, states, cumA);
  // 5. inter-chunk scan (in place)
  scan<<<dim3(4, HH, BB), 256, 0, stream>>>(states, cumA);
  // 6. Y_off + D-term (MFMA)
  yoff<<<dim3(HH, NC, BB), 256, 0, stream>>>(Cb, states, cumA, xs, Dp, y);
  // 7. gate + RMSNorm (normed overwrites states region)
  gatenorm<<<ROWS, 256, 0, stream>>>(y, zb, nsc, normb);
  // 8. out_proj GEMM (MFMA, fp32 out)
  gemm_mfma<1><<<dim3(DM / 128, ROWS / 128), 256, 0, stream>>>(
      (const short*)normb, (const short*)BtOut, DIN, nullptr, nullptr, nullptr, out);

  (void)in_sizes; (void)n_in; (void)out_size; (void)ws_size;
}